// Round 2
// baseline (1468.740 us; speedup 1.0000x reference)
//
#include <hip/hip_runtime.h>
#include <hip/hip_bf16.h>

// Pipeline (all node vectors padded to stride 4; v.w carries dinv where noted):
//  deg_r[s] += (s!=d)                       (16-way replicated atomics)
//  dinv = rsqrt(sum_r deg_r)
//  a3 = x@W0a ; y3 = x@W1a, y3.w = dinv     ([N,64]->[N,3])
//  t1_r[d] += -y3[s].w*dinv[d]*y3[s].xyz    (16-way replicated atomics)
//  h1 = relu(a3 + sum_r t1_r + b1), h1.w = dinv
//  t2_r[d] += -h1[s].w*dinv[d]*h1[s].xyz
//  t2 = sum_r t2_r
//  h2 = relu(h1@W0b + t2@W1b + b2) ; out = h2@Wl + bl   (fused k_final)

#define REP 16

__global__ void k_deg(const int* __restrict__ ei, float* __restrict__ degrep,
                      int E, int N) {
    int e = blockIdx.x * blockDim.x + threadIdx.x;
    if (e >= E) return;
    int s = ei[e], d = ei[E + e];
    float* deg = degrep + (size_t)(blockIdx.x & (REP - 1)) * N;
    if (s != d) atomicAdd(&deg[s], 1.0f);
}

__global__ void k_dinv(const float* __restrict__ degrep, float* __restrict__ dinv,
                       int n, int N) {
    int i = blockIdx.x * blockDim.x + threadIdx.x;
    if (i >= n) return;
    float dg = 0.f;
#pragma unroll
    for (int r = 0; r < REP; r++) dg += degrep[(size_t)r * N + i];
    dinv[i] = dg > 0.f ? rsqrtf(dg) : 0.f;
}

// x[N,64] @ (W0a|W1a)[64,3] -> a3v[N,4], y3v[N,4] (y3v.w = dinv)
__global__ void k_gemm1(const float* __restrict__ x, const float* __restrict__ W0a,
                        const float* __restrict__ W1a, const float* __restrict__ dinv,
                        float4* __restrict__ a3v, float4* __restrict__ y3v, int n) {
    __shared__ float w0[192], w1[192];
    int t = threadIdx.x;
    if (t < 192) { w0[t] = W0a[t]; w1[t] = W1a[t]; }
    __syncthreads();
    int node = blockIdx.x * blockDim.x + t;
    if (node >= n) return;
    const float4* xr = (const float4*)(x + (size_t)node * 64);
    float a0 = 0.f, a1 = 0.f, a2 = 0.f, c0 = 0.f, c1 = 0.f, c2 = 0.f;
#pragma unroll
    for (int i = 0; i < 16; i++) {
        float4 v = xr[i];
        float xs[4] = {v.x, v.y, v.z, v.w};
#pragma unroll
        for (int c = 0; c < 4; c++) {
            int f = i * 4 + c;
            float xi = xs[c];
            a0 += xi * w0[f * 3 + 0];
            a1 += xi * w0[f * 3 + 1];
            a2 += xi * w0[f * 3 + 2];
            c0 += xi * w1[f * 3 + 0];
            c1 += xi * w1[f * 3 + 1];
            c2 += xi * w1[f * 3 + 2];
        }
    }
    a3v[node] = make_float4(a0, a1, a2, 0.f);
    y3v[node] = make_float4(c0, c1, c2, dinv[node]);
}

// trep[r][d][0..2] += -v4[s].w*dinv[d] * v4[s].xyz
__global__ void k_scatter(const int* __restrict__ ei, const float* __restrict__ dinv,
                          const float4* __restrict__ v4, float* __restrict__ trep,
                          int E, int N) {
    int e = blockIdx.x * blockDim.x + threadIdx.x;
    if (e >= E) return;
    int s = ei[e], d = ei[E + e];
    if (s == d) return;
    float4 v = v4[s];
    float nm = -v.w * dinv[d];
    if (nm == 0.f) return;
    float* t = trep + (((size_t)(blockIdx.x & (REP - 1)) * N + d) << 2);
    atomicAdd(t + 0, nm * v.x);
    atomicAdd(t + 1, nm * v.y);
    atomicAdd(t + 2, nm * v.z);
}

__global__ void k_h1(const float4* __restrict__ a3v, const float4* __restrict__ t1rep,
                     const float* __restrict__ b1, const float* __restrict__ dinv,
                     float4* __restrict__ h1v, int n, int N) {
    int i = blockIdx.x * blockDim.x + threadIdx.x;
    if (i >= n) return;
    float4 a = a3v[i];
    float s0 = a.x, s1 = a.y, s2 = a.z;
#pragma unroll
    for (int r = 0; r < REP; r++) {
        float4 t = t1rep[(size_t)r * N + i];
        s0 += t.x; s1 += t.y; s2 += t.z;
    }
    h1v[i] = make_float4(fmaxf(s0 + b1[0], 0.f), fmaxf(s1 + b1[1], 0.f),
                         fmaxf(s2 + b1[2], 0.f), dinv[i]);
}

__global__ void k_t2red(const float4* __restrict__ t2rep, float4* __restrict__ t2r,
                        int n, int N) {
    int i = blockIdx.x * blockDim.x + threadIdx.x;
    if (i >= n) return;
    float s0 = 0.f, s1 = 0.f, s2 = 0.f;
#pragma unroll
    for (int r = 0; r < REP; r++) {
        float4 t = t2rep[(size_t)r * N + i];
        s0 += t.x; s1 += t.y; s2 += t.z;
    }
    t2r[i] = make_float4(s0, s1, s2, 0.f);
}

// Per block: 32 nodes. Phase 1: h2T[k][n] = relu(z) staged in LDS (k-major).
// Phase 2: each thread owns output cols (t, t+256), k-loop with LDS broadcast.
__global__ __launch_bounds__(256) void k_final(
    const float* __restrict__ h1, const float* __restrict__ t2,
    const float* __restrict__ W0b, const float* __restrict__ W1b,
    const float* __restrict__ b2, const float* __restrict__ Wl,
    const float* __restrict__ bl, float* __restrict__ out, int n) {
    __shared__ float h2T[256][32];  // 32 KB, k-major broadcast reads
    __shared__ float u6[32][6];     // [h1(3) | t2(3)] per node
    int t = threadIdx.x;
    int n0 = blockIdx.x * 32;
    if (t < 96) {
        int nn = t / 3, k = t % 3;
        int g = n0 + nn;
        float hv = 0.f, tv = 0.f;
        if (g < n) { hv = h1[g * 4 + k]; tv = t2[g * 4 + k]; }
        u6[nn][k] = hv;
        u6[nn][3 + k] = tv;
    }
    __syncthreads();
    {
        float w00 = W0b[t], w01 = W0b[256 + t], w02 = W0b[512 + t];
        float w10 = W1b[t], w11 = W1b[256 + t], w12 = W1b[512 + t];
        float bk = b2[t];
#pragma unroll
        for (int nn = 0; nn < 32; nn++) {
            float z = bk + u6[nn][0] * w00 + u6[nn][1] * w01 + u6[nn][2] * w02
                         + u6[nn][3] * w10 + u6[nn][4] * w11 + u6[nn][5] * w12;
            h2T[t][nn] = fmaxf(z, 0.f);
        }
    }
    __syncthreads();
    float acc0[32], acc1[32];
#pragma unroll
    for (int nn = 0; nn < 32; nn++) { acc0[nn] = 0.f; acc1[nn] = 0.f; }
    const float* wlc = Wl + t;
#pragma unroll 2
    for (int k = 0; k < 256; k++) {
        float wl0 = wlc[(size_t)k * 512];
        float wl1 = wlc[(size_t)k * 512 + 256];
#pragma unroll
        for (int nn = 0; nn < 32; nn++) {
            float h = h2T[k][nn];
            acc0[nn] += h * wl0;
            acc1[nn] += h * wl1;
        }
    }
    float bl0 = bl[t], bl1 = bl[t + 256];
#pragma unroll
    for (int nn = 0; nn < 32; nn++) {
        int g = n0 + nn;
        if (g < n) {
            out[(size_t)g * 512 + t] = acc0[nn] + bl0;
            out[(size_t)g * 512 + 256 + t] = acc1[nn] + bl1;
        }
    }
}

extern "C" void kernel_launch(void* const* d_in, const int* in_sizes, int n_in,
                              void* d_out, int out_size, void* d_ws, size_t ws_size,
                              hipStream_t stream) {
    const float* x   = (const float*)d_in[0];
    const int*   ei  = (const int*)d_in[1];
    const float* W0a = (const float*)d_in[2];
    const float* W1a = (const float*)d_in[3];
    const float* b1  = (const float*)d_in[4];
    const float* W0b = (const float*)d_in[5];
    const float* W1b = (const float*)d_in[6];
    const float* b2  = (const float*)d_in[7];
    const float* Wl  = (const float*)d_in[8];
    const float* bl  = (const float*)d_in[9];
    float* out = (float*)d_out;

    const int N = in_sizes[0] / 64;   // 100000
    const int E = in_sizes[1] / 2;    // 3200000

    float* ws     = (float*)d_ws;
    float* degrep = ws;                          // REP*N
    float* t1rep  = ws + (size_t)REP * N;        // REP*4N
    float* t2rep  = t1rep + (size_t)REP * 4 * N; // REP*4N
    float* dinv   = t2rep + (size_t)REP * 4 * N; // N
    float* a3v    = dinv + N;                    // 4N
    float* y3v    = a3v + (size_t)4 * N;         // 4N
    float* h1v    = y3v + (size_t)4 * N;         // 4N
    float* t2r    = h1v + (size_t)4 * N;         // 4N   (total 161N = 64.4 MB)

    // zero the atomic accumulation replicas (deg + t1 + t2 = 144N floats)
    hipMemsetAsync(ws, 0, (size_t)(REP * 9) * N * sizeof(float), stream);

    int eb = (E + 255) / 256, nb = (N + 255) / 256;
    k_deg<<<eb, 256, 0, stream>>>(ei, degrep, E, N);
    k_dinv<<<nb, 256, 0, stream>>>(degrep, dinv, N, N);
    k_gemm1<<<nb, 256, 0, stream>>>(x, W0a, W1a, dinv, (float4*)a3v, (float4*)y3v, N);
    k_scatter<<<eb, 256, 0, stream>>>(ei, dinv, (const float4*)y3v, t1rep, E, N);
    k_h1<<<nb, 256, 0, stream>>>((const float4*)a3v, (const float4*)t1rep, b1, dinv,
                                 (float4*)h1v, N, N);
    k_scatter<<<eb, 256, 0, stream>>>(ei, dinv, (const float4*)h1v, t2rep, E, N);
    k_t2red<<<nb, 256, 0, stream>>>((const float4*)t2rep, (float4*)t2r, N, N);
    k_final<<<(N + 31) / 32, 256, 0, stream>>>(h1v, t2r, W0b, W1b, b2, Wl, bl, out, N);
}

// Round 3
// 586.626 us; speedup vs baseline: 2.5037x; 2.5037x over previous
//
#include <hip/hip_runtime.h>
#include <hip/hip_bf16.h>

// Atomic-free (well, ~600K instead of 22.4M) pipeline:
//  1. k_hist : per-block LDS histograms of dst-bucket and src-bucket (bucket = id>>7)
//  2. k_scan : exclusive scan of both histograms -> bucket start offsets + cursors
//  3. k_place: counting-sort edges into dstbin (u32: dlow<<20|src) and srcbin (u8: slow)
//  4. k_deginv: per src-bucket LDS count -> dinv = rsqrt(deg)
//  5. k_gemm1: a3 = x@W0a, y3 = x@W1a (y3.w = dinv)           [N,64]->[N,3]
//  6. k_tgather(P1): per dst-bucket LDS accumulate t1, fuse h1 = relu(a3+t1+b1), h1.w=dinv
//  7. k_tgather(P2): same for t2
//  8. k_final : h2 = relu(h1@W0b + t2@W1b + b2); out = h2@Wl + bl

#define MAXNB 1024          // max buckets (supports N <= 131072)
#define BSH 7
#define BSZ 128             // nodes per bucket
#define SRC_BITS 20         // supports N < 2^20
#define SRC_MASK ((1u << SRC_BITS) - 1u)
#define EPB 16384           // edges per block in hist/place

__global__ __launch_bounds__(256) void k_hist(const int* __restrict__ ei, int E, int NB,
                                              unsigned* __restrict__ ghistD,
                                              unsigned* __restrict__ ghistS) {
    __shared__ unsigned hD[MAXNB], hS[MAXNB];
    int t = threadIdx.x;
    for (int i = t; i < NB; i += 256) { hD[i] = 0u; hS[i] = 0u; }
    __syncthreads();
    int e0 = blockIdx.x * EPB, e1 = min(e0 + EPB, E);
    for (int e = e0 + t; e < e1; e += 256) {
        int s = ei[e], d = ei[E + e];
        if (s != d) {
            atomicAdd(&hD[d >> BSH], 1u);
            atomicAdd(&hS[s >> BSH], 1u);
        }
    }
    __syncthreads();
    for (int i = t; i < NB; i += 256) {
        if (hD[i]) atomicAdd(&ghistD[i], hD[i]);
        if (hS[i]) atomicAdd(&ghistS[i], hS[i]);
    }
}

__global__ __launch_bounds__(1024) void k_scan(const unsigned* __restrict__ ghistD,
                                               const unsigned* __restrict__ ghistS,
                                               unsigned* __restrict__ startD,
                                               unsigned* __restrict__ startS,
                                               unsigned* __restrict__ cursorD,
                                               unsigned* __restrict__ cursorS, int NB) {
    __shared__ unsigned a[MAXNB], b[MAXNB];
    int t = threadIdx.x;
    // ---- D ----
    for (int i = t; i < NB; i += 1024) a[i] = ghistD[i];
    __syncthreads();
    unsigned* s = a; unsigned* d = b;
    for (int off = 1; off < NB; off <<= 1) {
        for (int i = t; i < NB; i += 1024)
            d[i] = s[i] + (i >= off ? s[i - off] : 0u);
        __syncthreads();
        unsigned* tmp = s; s = d; d = tmp;
    }
    for (int i = t; i < NB; i += 1024) {
        unsigned ex = (i == 0) ? 0u : s[i - 1];
        startD[i] = ex; cursorD[i] = ex;
    }
    if (t == 0) startD[NB] = s[NB - 1];
    __syncthreads();
    // ---- S ----
    for (int i = t; i < NB; i += 1024) a[i] = ghistS[i];
    __syncthreads();
    s = a; d = b;
    for (int off = 1; off < NB; off <<= 1) {
        for (int i = t; i < NB; i += 1024)
            d[i] = s[i] + (i >= off ? s[i - off] : 0u);
        __syncthreads();
        unsigned* tmp = s; s = d; d = tmp;
    }
    for (int i = t; i < NB; i += 1024) {
        unsigned ex = (i == 0) ? 0u : s[i - 1];
        startS[i] = ex; cursorS[i] = ex;
    }
    if (t == 0) startS[NB] = s[NB - 1];
}

__global__ __launch_bounds__(256) void k_place(const int* __restrict__ ei, int E, int NB,
                                               unsigned* __restrict__ cursorD,
                                               unsigned* __restrict__ cursorS,
                                               unsigned* __restrict__ dstbin,
                                               unsigned char* __restrict__ srcbin) {
    __shared__ unsigned hD[MAXNB], hS[MAXNB], bD[MAXNB], bS[MAXNB];
    int t = threadIdx.x;
    for (int i = t; i < NB; i += 256) { hD[i] = 0u; hS[i] = 0u; }
    __syncthreads();
    int e0 = blockIdx.x * EPB, e1 = min(e0 + EPB, E);
    for (int e = e0 + t; e < e1; e += 256) {
        int s = ei[e], d = ei[E + e];
        if (s != d) {
            atomicAdd(&hD[d >> BSH], 1u);
            atomicAdd(&hS[s >> BSH], 1u);
        }
    }
    __syncthreads();
    for (int i = t; i < NB; i += 256) {
        unsigned h = hD[i];
        bD[i] = h ? atomicAdd(&cursorD[i], h) : 0u;
        h = hS[i];
        bS[i] = h ? atomicAdd(&cursorS[i], h) : 0u;
        hD[i] = 0u; hS[i] = 0u;   // reuse as intra-block cursors
    }
    __syncthreads();
    for (int e = e0 + t; e < e1; e += 256) {
        int s = ei[e], d = ei[E + e];
        if (s != d) {
            int bk = d >> BSH;
            unsigned pos = bD[bk] + atomicAdd(&hD[bk], 1u);
            dstbin[pos] = ((unsigned)(d & (BSZ - 1)) << SRC_BITS) | (unsigned)s;
            int bs = s >> BSH;
            unsigned ps = bS[bs] + atomicAdd(&hS[bs], 1u);
            srcbin[ps] = (unsigned char)(s & (BSZ - 1));
        }
    }
}

__global__ __launch_bounds__(256) void k_deginv(const unsigned char* __restrict__ srcbin,
                                                const unsigned* __restrict__ startS,
                                                float* __restrict__ dinv, int N) {
    __shared__ unsigned cnt[BSZ];
    int t = threadIdx.x, b = blockIdx.x;
    if (t < BSZ) cnt[t] = 0u;
    __syncthreads();
    unsigned i0 = startS[b], i1 = startS[b + 1];
    for (unsigned i = i0 + t; i < i1; i += 256) atomicAdd(&cnt[srcbin[i]], 1u);
    __syncthreads();
    int g = b * BSZ + t;
    if (t < BSZ && g < N) dinv[g] = cnt[t] ? rsqrtf((float)cnt[t]) : 0.f;
}

// x[N,64] @ (W0a|W1a)[64,3] -> a3v[N,4], y3v[N,4] (y3v.w = dinv)
__global__ void k_gemm1(const float* __restrict__ x, const float* __restrict__ W0a,
                        const float* __restrict__ W1a, const float* __restrict__ dinv,
                        float4* __restrict__ a3v, float4* __restrict__ y3v, int n) {
    __shared__ float w0[192], w1[192];
    int t = threadIdx.x;
    if (t < 192) { w0[t] = W0a[t]; w1[t] = W1a[t]; }
    __syncthreads();
    int node = blockIdx.x * blockDim.x + t;
    if (node >= n) return;
    const float4* xr = (const float4*)(x + (size_t)node * 64);
    float a0 = 0.f, a1 = 0.f, a2 = 0.f, c0 = 0.f, c1 = 0.f, c2 = 0.f;
#pragma unroll
    for (int i = 0; i < 16; i++) {
        float4 v = xr[i];
        float xs[4] = {v.x, v.y, v.z, v.w};
#pragma unroll
        for (int c = 0; c < 4; c++) {
            int f = i * 4 + c;
            float xi = xs[c];
            a0 += xi * w0[f * 3 + 0];
            a1 += xi * w0[f * 3 + 1];
            a2 += xi * w0[f * 3 + 2];
            c0 += xi * w1[f * 3 + 0];
            c1 += xi * w1[f * 3 + 1];
            c2 += xi * w1[f * 3 + 2];
        }
    }
    a3v[node] = make_float4(a0, a1, a2, 0.f);
    y3v[node] = make_float4(c0, c1, c2, dinv[node]);
}

// One block per dst-bucket: LDS-accumulate t = sum(-dinv[s]*dinv[d]*v.xyz).
// phase 1: out = relu(a3 + t + b1), .w = dinv ;  phase 2: out = t
__global__ __launch_bounds__(256) void k_tgather(const unsigned* __restrict__ dstbin,
                                                 const unsigned* __restrict__ startD,
                                                 const float4* __restrict__ v4,
                                                 const float* __restrict__ dinv,
                                                 const float4* __restrict__ a3v,
                                                 const float* __restrict__ b1,
                                                 float4* __restrict__ outv, int N,
                                                 int phase) {
    __shared__ float acc[BSZ][4];
    __shared__ float dl[BSZ];
    int t = threadIdx.x, b = blockIdx.x;
    for (int i = t; i < BSZ * 4; i += 256) ((float*)acc)[i] = 0.f;
    if (t < BSZ) {
        int g = b * BSZ + t;
        dl[t] = (g < N) ? dinv[g] : 0.f;
    }
    __syncthreads();
    unsigned i0 = startD[b], i1 = startD[b + 1];
    for (unsigned i = i0 + t; i < i1; i += 256) {
        unsigned p = dstbin[i];
        int s = (int)(p & SRC_MASK);
        int di = (int)(p >> SRC_BITS);
        float4 v = v4[s];
        float nm = -v.w * dl[di];
        if (nm != 0.f) {
            atomicAdd(&acc[di][0], nm * v.x);
            atomicAdd(&acc[di][1], nm * v.y);
            atomicAdd(&acc[di][2], nm * v.z);
        }
    }
    __syncthreads();
    if (t < BSZ) {
        int g = b * BSZ + t;
        if (g < N) {
            float s0 = acc[t][0], s1 = acc[t][1], s2 = acc[t][2];
            if (phase == 1) {
                float4 a = a3v[g];
                outv[g] = make_float4(fmaxf(s0 + a.x + b1[0], 0.f),
                                      fmaxf(s1 + a.y + b1[1], 0.f),
                                      fmaxf(s2 + a.z + b1[2], 0.f), dl[t]);
            } else {
                outv[g] = make_float4(s0, s1, s2, 0.f);
            }
        }
    }
}

// Per block: 32 nodes. Phase 1: h2T[k][n] staged in LDS (k-major).
// Phase 2: each thread owns output cols (t, t+256).
__global__ __launch_bounds__(256) void k_final(
    const float* __restrict__ h1, const float* __restrict__ t2,
    const float* __restrict__ W0b, const float* __restrict__ W1b,
    const float* __restrict__ b2, const float* __restrict__ Wl,
    const float* __restrict__ bl, float* __restrict__ out, int n) {
    __shared__ float h2T[256][32];
    __shared__ float u6[32][6];
    int t = threadIdx.x;
    int n0 = blockIdx.x * 32;
    if (t < 96) {
        int nn = t / 3, k = t % 3;
        int g = n0 + nn;
        float hv = 0.f, tv = 0.f;
        if (g < n) { hv = h1[g * 4 + k]; tv = t2[g * 4 + k]; }
        u6[nn][k] = hv;
        u6[nn][3 + k] = tv;
    }
    __syncthreads();
    {
        float w00 = W0b[t], w01 = W0b[256 + t], w02 = W0b[512 + t];
        float w10 = W1b[t], w11 = W1b[256 + t], w12 = W1b[512 + t];
        float bk = b2[t];
#pragma unroll
        for (int nn = 0; nn < 32; nn++) {
            float z = bk + u6[nn][0] * w00 + u6[nn][1] * w01 + u6[nn][2] * w02
                         + u6[nn][3] * w10 + u6[nn][4] * w11 + u6[nn][5] * w12;
            h2T[t][nn] = fmaxf(z, 0.f);
        }
    }
    __syncthreads();
    float acc0[32], acc1[32];
#pragma unroll
    for (int nn = 0; nn < 32; nn++) { acc0[nn] = 0.f; acc1[nn] = 0.f; }
    const float* wlc = Wl + t;
#pragma unroll 2
    for (int k = 0; k < 256; k++) {
        float wl0 = wlc[(size_t)k * 512];
        float wl1 = wlc[(size_t)k * 512 + 256];
#pragma unroll
        for (int nn = 0; nn < 32; nn++) {
            float h = h2T[k][nn];
            acc0[nn] += h * wl0;
            acc1[nn] += h * wl1;
        }
    }
    float bl0 = bl[t], bl1 = bl[t + 256];
#pragma unroll
    for (int nn = 0; nn < 32; nn++) {
        int g = n0 + nn;
        if (g < n) {
            out[(size_t)g * 512 + t] = acc0[nn] + bl0;
            out[(size_t)g * 512 + 256 + t] = acc1[nn] + bl1;
        }
    }
}

extern "C" void kernel_launch(void* const* d_in, const int* in_sizes, int n_in,
                              void* d_out, int out_size, void* d_ws, size_t ws_size,
                              hipStream_t stream) {
    const float* x   = (const float*)d_in[0];
    const int*   ei  = (const int*)d_in[1];
    const float* W0a = (const float*)d_in[2];
    const float* W1a = (const float*)d_in[3];
    const float* b1  = (const float*)d_in[4];
    const float* W0b = (const float*)d_in[5];
    const float* W1b = (const float*)d_in[6];
    const float* b2  = (const float*)d_in[7];
    const float* Wl  = (const float*)d_in[8];
    const float* bl  = (const float*)d_in[9];
    float* out = (float*)d_out;

    const int N = in_sizes[0] / 64;   // 100000
    const int E = in_sizes[1] / 2;    // 3200000
    const int NB = (N + BSZ - 1) >> BSH;

    char* base = (char*)d_ws;
    size_t off = 0;
    auto alloc = [&](size_t bytes) {
        void* p = base + off;
        off = (off + bytes + 255) & ~(size_t)255;
        return p;
    };
    unsigned* ghistD  = (unsigned*)alloc(MAXNB * 4);
    unsigned* ghistS  = (unsigned*)alloc(MAXNB * 4);
    unsigned* startD  = (unsigned*)alloc((MAXNB + 1) * 4);
    unsigned* startS  = (unsigned*)alloc((MAXNB + 1) * 4);
    unsigned* cursorD = (unsigned*)alloc(MAXNB * 4);
    unsigned* cursorS = (unsigned*)alloc(MAXNB * 4);
    unsigned* dstbin  = (unsigned*)alloc((size_t)E * 4);
    unsigned char* srcbin = (unsigned char*)alloc((size_t)E);
    float* dinv = (float*)alloc((size_t)N * 4);
    float* a3v  = (float*)alloc((size_t)N * 16);
    float* y3v  = (float*)alloc((size_t)N * 16);
    float* h1v  = (float*)alloc((size_t)N * 16);
    float* t2r  = (float*)alloc((size_t)N * 16);

    hipMemsetAsync(ghistD, 0, 2 * MAXNB * 4, stream);  // ghistD + ghistS (contiguous alloc)
    hipMemsetAsync(ghistS, 0, MAXNB * 4, stream);      // (in case of alignment padding)

    const int CB = (E + EPB - 1) / EPB;
    const int nb = (N + 255) / 256;

    k_hist<<<CB, 256, 0, stream>>>(ei, E, NB, ghistD, ghistS);
    k_scan<<<1, 1024, 0, stream>>>(ghistD, ghistS, startD, startS, cursorD, cursorS, NB);
    k_place<<<CB, 256, 0, stream>>>(ei, E, NB, cursorD, cursorS, dstbin, srcbin);
    k_deginv<<<NB, 256, 0, stream>>>(srcbin, startS, dinv, N);
    k_gemm1<<<nb, 256, 0, stream>>>(x, W0a, W1a, dinv, (float4*)a3v, (float4*)y3v, N);
    k_tgather<<<NB, 256, 0, stream>>>(dstbin, startD, (const float4*)y3v, dinv,
                                      (const float4*)a3v, b1, (float4*)h1v, N, 1);
    k_tgather<<<NB, 256, 0, stream>>>(dstbin, startD, (const float4*)h1v, dinv,
                                      (const float4*)a3v, b1, (float4*)t2r, N, 2);
    k_final<<<(N + 31) / 32, 256, 0, stream>>>(h1v, t2r, W0b, W1b, b2, Wl, bl, out, N);
}

// Round 4
// 364.123 us; speedup vs baseline: 4.0336x; 1.6111x over previous
//
#include <hip/hip_runtime.h>
#include <hip/hip_bf16.h>

// Pipeline:
//  1. k_hist : per-block LDS histograms of dst-bucket and src-bucket (bucket = id>>7)
//  2. k_scan : exclusive scan -> bucket start offsets + cursors
//  3. k_place: counting-sort edges into dstbin (u32: dlow<<20|src) and srcbin (u8: slow)
//  4. k_deginv: per src-bucket LDS count -> dinv = rsqrt(deg)
//  5. k_gemm1: a3 = x@W0a, y3 = x@W1a (y3.w = dinv)           [N,64]->[N,3]
//  6. k_tgather(P1): per dst-bucket LDS accumulate t1, fuse h1 = relu(a3+t1+b1), h1.w=dinv
//  7. k_tgather(P2): same for t2
//  8. k_prep : WlT[512][256] bf16 = transpose(Wl)
//  9. k_final_mfma: h2 = relu(h1@W0b + t2@W1b + b2) -> bf16 LDS (XOR-swizzled);
//     out = h2@Wl + bl via mfma_f32_16x16x32_bf16 (A from LDS, B from WlT in L2)

#define MAXNB 1024
#define BSH 7
#define BSZ 128
#define SRC_BITS 20
#define SRC_MASK ((1u << SRC_BITS) - 1u)
#define EPB 16384

typedef __attribute__((ext_vector_type(8))) short short8;
typedef __attribute__((ext_vector_type(4))) float f32x4;

static __device__ inline unsigned short f2bf(float f) {
    union { float f; unsigned u; } v; v.f = f;
    unsigned r = (v.u + 0x7fffu + ((v.u >> 16) & 1u)) >> 16;
    return (unsigned short)r;
}

__global__ __launch_bounds__(256) void k_hist(const int* __restrict__ ei, int E, int NB,
                                              unsigned* __restrict__ ghistD,
                                              unsigned* __restrict__ ghistS) {
    __shared__ unsigned hD[MAXNB], hS[MAXNB];
    int t = threadIdx.x;
    for (int i = t; i < NB; i += 256) { hD[i] = 0u; hS[i] = 0u; }
    __syncthreads();
    int e0 = blockIdx.x * EPB, e1 = min(e0 + EPB, E);
    for (int e = e0 + t; e < e1; e += 256) {
        int s = ei[e], d = ei[E + e];
        if (s != d) {
            atomicAdd(&hD[d >> BSH], 1u);
            atomicAdd(&hS[s >> BSH], 1u);
        }
    }
    __syncthreads();
    for (int i = t; i < NB; i += 256) {
        if (hD[i]) atomicAdd(&ghistD[i], hD[i]);
        if (hS[i]) atomicAdd(&ghistS[i], hS[i]);
    }
}

__global__ __launch_bounds__(1024) void k_scan(const unsigned* __restrict__ ghistD,
                                               const unsigned* __restrict__ ghistS,
                                               unsigned* __restrict__ startD,
                                               unsigned* __restrict__ startS,
                                               unsigned* __restrict__ cursorD,
                                               unsigned* __restrict__ cursorS, int NB) {
    __shared__ unsigned a[MAXNB], b[MAXNB];
    int t = threadIdx.x;
    for (int i = t; i < NB; i += 1024) a[i] = ghistD[i];
    __syncthreads();
    unsigned* s = a; unsigned* d = b;
    for (int off = 1; off < NB; off <<= 1) {
        for (int i = t; i < NB; i += 1024)
            d[i] = s[i] + (i >= off ? s[i - off] : 0u);
        __syncthreads();
        unsigned* tmp = s; s = d; d = tmp;
    }
    for (int i = t; i < NB; i += 1024) {
        unsigned ex = (i == 0) ? 0u : s[i - 1];
        startD[i] = ex; cursorD[i] = ex;
    }
    if (t == 0) startD[NB] = s[NB - 1];
    __syncthreads();
    for (int i = t; i < NB; i += 1024) a[i] = ghistS[i];
    __syncthreads();
    s = a; d = b;
    for (int off = 1; off < NB; off <<= 1) {
        for (int i = t; i < NB; i += 1024)
            d[i] = s[i] + (i >= off ? s[i - off] : 0u);
        __syncthreads();
        unsigned* tmp = s; s = d; d = tmp;
    }
    for (int i = t; i < NB; i += 1024) {
        unsigned ex = (i == 0) ? 0u : s[i - 1];
        startS[i] = ex; cursorS[i] = ex;
    }
    if (t == 0) startS[NB] = s[NB - 1];
}

__global__ __launch_bounds__(256) void k_place(const int* __restrict__ ei, int E, int NB,
                                               unsigned* __restrict__ cursorD,
                                               unsigned* __restrict__ cursorS,
                                               unsigned* __restrict__ dstbin,
                                               unsigned char* __restrict__ srcbin) {
    __shared__ unsigned hD[MAXNB], hS[MAXNB], bD[MAXNB], bS[MAXNB];
    int t = threadIdx.x;
    for (int i = t; i < NB; i += 256) { hD[i] = 0u; hS[i] = 0u; }
    __syncthreads();
    int e0 = blockIdx.x * EPB, e1 = min(e0 + EPB, E);
    for (int e = e0 + t; e < e1; e += 256) {
        int s = ei[e], d = ei[E + e];
        if (s != d) {
            atomicAdd(&hD[d >> BSH], 1u);
            atomicAdd(&hS[s >> BSH], 1u);
        }
    }
    __syncthreads();
    for (int i = t; i < NB; i += 256) {
        unsigned h = hD[i];
        bD[i] = h ? atomicAdd(&cursorD[i], h) : 0u;
        h = hS[i];
        bS[i] = h ? atomicAdd(&cursorS[i], h) : 0u;
        hD[i] = 0u; hS[i] = 0u;
    }
    __syncthreads();
    for (int e = e0 + t; e < e1; e += 256) {
        int s = ei[e], d = ei[E + e];
        if (s != d) {
            int bk = d >> BSH;
            unsigned pos = bD[bk] + atomicAdd(&hD[bk], 1u);
            dstbin[pos] = ((unsigned)(d & (BSZ - 1)) << SRC_BITS) | (unsigned)s;
            int bs = s >> BSH;
            unsigned ps = bS[bs] + atomicAdd(&hS[bs], 1u);
            srcbin[ps] = (unsigned char)(s & (BSZ - 1));
        }
    }
}

__global__ __launch_bounds__(256) void k_deginv(const unsigned char* __restrict__ srcbin,
                                                const unsigned* __restrict__ startS,
                                                float* __restrict__ dinv, int N) {
    __shared__ unsigned cnt[BSZ];
    int t = threadIdx.x, b = blockIdx.x;
    if (t < BSZ) cnt[t] = 0u;
    __syncthreads();
    unsigned i0 = startS[b], i1 = startS[b + 1];
    for (unsigned i = i0 + t; i < i1; i += 256) atomicAdd(&cnt[srcbin[i]], 1u);
    __syncthreads();
    int g = b * BSZ + t;
    if (t < BSZ && g < N) dinv[g] = cnt[t] ? rsqrtf((float)cnt[t]) : 0.f;
}

__global__ void k_gemm1(const float* __restrict__ x, const float* __restrict__ W0a,
                        const float* __restrict__ W1a, const float* __restrict__ dinv,
                        float4* __restrict__ a3v, float4* __restrict__ y3v, int n) {
    __shared__ float w0[192], w1[192];
    int t = threadIdx.x;
    if (t < 192) { w0[t] = W0a[t]; w1[t] = W1a[t]; }
    __syncthreads();
    int node = blockIdx.x * blockDim.x + t;
    if (node >= n) return;
    const float4* xr = (const float4*)(x + (size_t)node * 64);
    float a0 = 0.f, a1 = 0.f, a2 = 0.f, c0 = 0.f, c1 = 0.f, c2 = 0.f;
#pragma unroll
    for (int i = 0; i < 16; i++) {
        float4 v = xr[i];
        float xs[4] = {v.x, v.y, v.z, v.w};
#pragma unroll
        for (int c = 0; c < 4; c++) {
            int f = i * 4 + c;
            float xi = xs[c];
            a0 += xi * w0[f * 3 + 0];
            a1 += xi * w0[f * 3 + 1];
            a2 += xi * w0[f * 3 + 2];
            c0 += xi * w1[f * 3 + 0];
            c1 += xi * w1[f * 3 + 1];
            c2 += xi * w1[f * 3 + 2];
        }
    }
    a3v[node] = make_float4(a0, a1, a2, 0.f);
    y3v[node] = make_float4(c0, c1, c2, dinv[node]);
}

__global__ __launch_bounds__(256) void k_tgather(const unsigned* __restrict__ dstbin,
                                                 const unsigned* __restrict__ startD,
                                                 const float4* __restrict__ v4,
                                                 const float* __restrict__ dinv,
                                                 const float4* __restrict__ a3v,
                                                 const float* __restrict__ b1,
                                                 float4* __restrict__ outv, int N,
                                                 int phase) {
    __shared__ float acc[BSZ][4];
    __shared__ float dl[BSZ];
    int t = threadIdx.x, b = blockIdx.x;
    for (int i = t; i < BSZ * 4; i += 256) ((float*)acc)[i] = 0.f;
    if (t < BSZ) {
        int g = b * BSZ + t;
        dl[t] = (g < N) ? dinv[g] : 0.f;
    }
    __syncthreads();
    unsigned i0 = startD[b], i1 = startD[b + 1];
    for (unsigned i = i0 + t; i < i1; i += 256) {
        unsigned p = dstbin[i];
        int s = (int)(p & SRC_MASK);
        int di = (int)(p >> SRC_BITS);
        float4 v = v4[s];
        float nm = -v.w * dl[di];
        if (nm != 0.f) {
            atomicAdd(&acc[di][0], nm * v.x);
            atomicAdd(&acc[di][1], nm * v.y);
            atomicAdd(&acc[di][2], nm * v.z);
        }
    }
    __syncthreads();
    if (t < BSZ) {
        int g = b * BSZ + t;
        if (g < N) {
            float s0 = acc[t][0], s1 = acc[t][1], s2 = acc[t][2];
            if (phase == 1) {
                float4 a = a3v[g];
                outv[g] = make_float4(fmaxf(s0 + a.x + b1[0], 0.f),
                                      fmaxf(s1 + a.y + b1[1], 0.f),
                                      fmaxf(s2 + a.z + b1[2], 0.f), dl[t]);
            } else {
                outv[g] = make_float4(s0, s1, s2, 0.f);
            }
        }
    }
}

// WlT[c][k] = bf16(Wl[k][c]); Wl is [256][512] f32. Tiled LDS transpose.
__global__ __launch_bounds__(256) void k_prep(const float* __restrict__ Wl,
                                              unsigned short* __restrict__ WlT) {
    __shared__ float tile[32][33];
    int t = threadIdx.x, tx = t & 31, ty = t >> 5;       // ty: 0..7
    int kb = (blockIdx.x & 7) * 32;                      // 256/32 = 8
    int cb = (blockIdx.x >> 3) * 32;                     // 512/32 = 16
#pragma unroll
    for (int r = 0; r < 4; r++) {
        int k = kb + ty + r * 8;
        tile[ty + r * 8][tx] = Wl[(size_t)k * 512 + cb + tx];
    }
    __syncthreads();
#pragma unroll
    for (int r = 0; r < 4; r++) {
        int c = cb + ty + r * 8;
        WlT[(size_t)c * 256 + kb + tx] = f2bf(tile[tx][ty + r * 8]);
    }
}

// 64 nodes/block, 256 threads (4 waves x 128 cols).
// Phase 1: h2[64][256] bf16 into XOR-swizzled LDS (byte ^= (row&7)<<4).
// Phase 2: MFMA 16x16x32 bf16, A from LDS, B from WlT (L2), + bl, store f32.
__global__ __launch_bounds__(256) void k_final_mfma(
    const float4* __restrict__ h1v, const float4* __restrict__ t2r,
    const float* __restrict__ W0b, const float* __restrict__ W1b,
    const float* __restrict__ b2, const unsigned short* __restrict__ WlT,
    const float* __restrict__ bl, float* __restrict__ out, int N) {
    __shared__ unsigned short h2s[64 * 256];   // 32 KB
    __shared__ float4 u4[64][2];               // [h1 | t2]
    char* h2b = (char*)h2s;
    int t = threadIdx.x;
    int n0 = blockIdx.x * 64;

    if (t < 64) {
        int g = n0 + t;
        u4[t][0] = (g < N) ? h1v[g] : make_float4(0.f, 0.f, 0.f, 0.f);
    } else if (t < 128) {
        int g = n0 + t - 64;
        u4[t - 64][1] = (g < N) ? t2r[g] : make_float4(0.f, 0.f, 0.f, 0.f);
    }
    __syncthreads();

    {   // phase 1: thread handles k0,k0+1 for 32 rows
        int k0 = (t & 127) * 2;
        int rh = (t >> 7) * 32;
        float w00a = W0b[k0],       w00b = W0b[k0 + 1];
        float w01a = W0b[256 + k0], w01b = W0b[256 + k0 + 1];
        float w02a = W0b[512 + k0], w02b = W0b[512 + k0 + 1];
        float w10a = W1b[k0],       w10b = W1b[k0 + 1];
        float w11a = W1b[256 + k0], w11b = W1b[256 + k0 + 1];
        float w12a = W1b[512 + k0], w12b = W1b[512 + k0 + 1];
        float bka = b2[k0], bkb = b2[k0 + 1];
        int kbyte = k0 * 2;
#pragma unroll
        for (int r = 0; r < 32; r++) {
            int rr = rh + r;
            float4 h = u4[rr][0];
            float4 v = u4[rr][1];
            float za = bka + h.x * w00a + h.y * w01a + h.z * w02a
                           + v.x * w10a + v.y * w11a + v.z * w12a;
            float zb = bkb + h.x * w00b + h.y * w01b + h.z * w02b
                           + v.x * w10b + v.y * w11b + v.z * w12b;
            za = fmaxf(za, 0.f); zb = fmaxf(zb, 0.f);
            unsigned pk = ((unsigned)f2bf(zb) << 16) | (unsigned)f2bf(za);
            int byte = rr * 512 + (kbyte ^ ((rr & 7) << 4));
            *(unsigned*)(h2b + byte) = pk;
        }
    }
    __syncthreads();

    // phase 2
    int w = t >> 6, l = t & 63;
    int lrow = l & 15, lkb = (l >> 4) * 8;    // k sub-offset (elements)
    int col0 = w * 128;
    f32x4 acc[4][8];
#pragma unroll
    for (int rt = 0; rt < 4; rt++)
#pragma unroll
        for (int ct = 0; ct < 8; ct++) acc[rt][ct] = (f32x4)0.f;

#pragma unroll
    for (int ks = 0; ks < 8; ks++) {
        int kel = ks * 32 + lkb;              // element offset in K
        short8 af[4];
#pragma unroll
        for (int rt = 0; rt < 4; rt++) {
            int r = rt * 16 + lrow;
            int byte = r * 512 + ((kel * 2) ^ ((r & 7) << 4));
            af[rt] = *(const short8*)(h2b + byte);
        }
        short8 bf[8];
#pragma unroll
        for (int ct = 0; ct < 8; ct++) {
            int c = col0 + ct * 16 + lrow;
            bf[ct] = *(const short8*)(WlT + (size_t)c * 256 + kel);
        }
#pragma unroll
        for (int rt = 0; rt < 4; rt++)
#pragma unroll
            for (int ct = 0; ct < 8; ct++)
                acc[rt][ct] = __builtin_amdgcn_mfma_f32_16x16x32_bf16(
                    af[rt], bf[ct], acc[rt][ct], 0, 0, 0);
    }

    float blv[8];
#pragma unroll
    for (int ct = 0; ct < 8; ct++) blv[ct] = bl[col0 + ct * 16 + lrow];
#pragma unroll
    for (int rt = 0; rt < 4; rt++) {
        int rbase = n0 + rt * 16 + (l >> 4) * 4;
#pragma unroll
        for (int j = 0; j < 4; j++) {
            int row = rbase + j;
            if (row < N) {
                float* orow = out + (size_t)row * 512 + col0 + lrow;
#pragma unroll
                for (int ct = 0; ct < 8; ct++)
                    orow[ct * 16] = acc[rt][ct][j] + blv[ct];
            }
        }
    }
}

extern "C" void kernel_launch(void* const* d_in, const int* in_sizes, int n_in,
                              void* d_out, int out_size, void* d_ws, size_t ws_size,
                              hipStream_t stream) {
    const float* x   = (const float*)d_in[0];
    const int*   ei  = (const int*)d_in[1];
    const float* W0a = (const float*)d_in[2];
    const float* W1a = (const float*)d_in[3];
    const float* b1  = (const float*)d_in[4];
    const float* W0b = (const float*)d_in[5];
    const float* W1b = (const float*)d_in[6];
    const float* b2  = (const float*)d_in[7];
    const float* Wl  = (const float*)d_in[8];
    const float* bl  = (const float*)d_in[9];
    float* out = (float*)d_out;

    const int N = in_sizes[0] / 64;
    const int E = in_sizes[1] / 2;
    const int NB = (N + BSZ - 1) >> BSH;

    char* base = (char*)d_ws;
    size_t off = 0;
    auto alloc = [&](size_t bytes) {
        void* p = base + off;
        off = (off + bytes + 255) & ~(size_t)255;
        return p;
    };
    unsigned* ghistD  = (unsigned*)alloc(MAXNB * 4);
    unsigned* ghistS  = (unsigned*)alloc(MAXNB * 4);
    unsigned* startD  = (unsigned*)alloc((MAXNB + 1) * 4);
    unsigned* startS  = (unsigned*)alloc((MAXNB + 1) * 4);
    unsigned* cursorD = (unsigned*)alloc(MAXNB * 4);
    unsigned* cursorS = (unsigned*)alloc(MAXNB * 4);
    unsigned* dstbin  = (unsigned*)alloc((size_t)E * 4);
    unsigned char* srcbin = (unsigned char*)alloc((size_t)E);
    float* dinv = (float*)alloc((size_t)N * 4);
    float* a3v  = (float*)alloc((size_t)N * 16);
    float* y3v  = (float*)alloc((size_t)N * 16);
    float* h1v  = (float*)alloc((size_t)N * 16);
    float* t2r  = (float*)alloc((size_t)N * 16);
    unsigned short* WlT = (unsigned short*)alloc(512 * 256 * 2);

    hipMemsetAsync(ghistD, 0, MAXNB * 4, stream);
    hipMemsetAsync(ghistS, 0, MAXNB * 4, stream);

    const int CB = (E + EPB - 1) / EPB;
    const int nb = (N + 255) / 256;

    k_prep<<<128, 256, 0, stream>>>(Wl, WlT);
    k_hist<<<CB, 256, 0, stream>>>(ei, E, NB, ghistD, ghistS);
    k_scan<<<1, 1024, 0, stream>>>(ghistD, ghistS, startD, startS, cursorD, cursorS, NB);
    k_place<<<CB, 256, 0, stream>>>(ei, E, NB, cursorD, cursorS, dstbin, srcbin);
    k_deginv<<<NB, 256, 0, stream>>>(srcbin, startS, dinv, N);
    k_gemm1<<<nb, 256, 0, stream>>>(x, W0a, W1a, dinv, (float4*)a3v, (float4*)y3v, N);
    k_tgather<<<NB, 256, 0, stream>>>(dstbin, startD, (const float4*)y3v, dinv,
                                      (const float4*)a3v, b1, (float4*)h1v, N, 1);
    k_tgather<<<NB, 256, 0, stream>>>(dstbin, startD, (const float4*)h1v, dinv,
                                      (const float4*)a3v, b1, (float4*)t2r, N, 2);
    k_final_mfma<<<(N + 63) / 64, 256, 0, stream>>>(
        (const float4*)h1v, (const float4*)t2r, W0b, W1b, b2, WlT, bl, out, N);
}

// Round 6
// 363.098 us; speedup vs baseline: 4.0450x; 1.0028x over previous
//
#include <hip/hip_runtime.h>
#include <hip/hip_bf16.h>

// Pipeline:
//  1. k_hist : per-block LDS histograms of dst-bucket and src-bucket (bucket = id>>7)
//  2. k_scan : exclusive scan -> bucket start offsets + cursors
//  3. k_place: counting-sort edges into dstbin (u32: dlow<<20|src) and srcbin (u8: slow)
//  4. k_deginv: per src-bucket LDS count (4-way replicated) -> dinv = rsqrt(deg)
//  5. k_gemm1: a3 = x@W0a, y3 = x@W1a (y3.w = dinv), 4 lanes/node + shfl reduce
//  6. k_tgather(P1): per dst-bucket LDS accumulate (4-way replicated) t1,
//     fuse h1 = relu(a3+t1+b1), h1.w = dinv
//  7. k_tgather(P2): same for t2
//  8. k_prep : WlT[512][256] bf16 = transpose(Wl)
//  9. k_final_mfma: 128 rows/block, 8 waves x (64x128) tiles, h2 -> bf16
//     XOR-swizzled LDS; out = h2@Wl + bl via mfma_f32_16x16x32_bf16

#define MAXNB 1024
#define BSH 7
#define BSZ 128
#define SRC_BITS 20
#define SRC_MASK ((1u << SRC_BITS) - 1u)
#define EPB 16384

typedef __attribute__((ext_vector_type(8))) short short8;
typedef __attribute__((ext_vector_type(4))) float f32x4;

static __device__ inline unsigned short f2bf(float f) {
    union { float f; unsigned u; } v; v.f = f;
    unsigned r = (v.u + 0x7fffu + ((v.u >> 16) & 1u)) >> 16;
    return (unsigned short)r;
}

__global__ __launch_bounds__(256) void k_hist(const int* __restrict__ ei, int E, int NB,
                                              unsigned* __restrict__ ghistD,
                                              unsigned* __restrict__ ghistS) {
    __shared__ unsigned hD[MAXNB], hS[MAXNB];
    int t = threadIdx.x;
    for (int i = t; i < NB; i += 256) { hD[i] = 0u; hS[i] = 0u; }
    __syncthreads();
    int e0 = blockIdx.x * EPB, e1 = min(e0 + EPB, E);
    for (int e = e0 + t; e < e1; e += 256) {
        int s = ei[e], d = ei[E + e];
        if (s != d) {
            atomicAdd(&hD[d >> BSH], 1u);
            atomicAdd(&hS[s >> BSH], 1u);
        }
    }
    __syncthreads();
    for (int i = t; i < NB; i += 256) {
        if (hD[i]) atomicAdd(&ghistD[i], hD[i]);
        if (hS[i]) atomicAdd(&ghistS[i], hS[i]);
    }
}

__global__ __launch_bounds__(1024) void k_scan(const unsigned* __restrict__ ghistD,
                                               const unsigned* __restrict__ ghistS,
                                               unsigned* __restrict__ startD,
                                               unsigned* __restrict__ startS,
                                               unsigned* __restrict__ cursorD,
                                               unsigned* __restrict__ cursorS, int NB) {
    __shared__ unsigned a[MAXNB], b[MAXNB];
    int t = threadIdx.x;
    for (int i = t; i < NB; i += 1024) a[i] = ghistD[i];
    __syncthreads();
    unsigned* s = a; unsigned* d = b;
    for (int off = 1; off < NB; off <<= 1) {
        for (int i = t; i < NB; i += 1024)
            d[i] = s[i] + (i >= off ? s[i - off] : 0u);
        __syncthreads();
        unsigned* tmp = s; s = d; d = tmp;
    }
    for (int i = t; i < NB; i += 1024) {
        unsigned ex = (i == 0) ? 0u : s[i - 1];
        startD[i] = ex; cursorD[i] = ex;
    }
    if (t == 0) startD[NB] = s[NB - 1];
    __syncthreads();
    for (int i = t; i < NB; i += 1024) a[i] = ghistS[i];
    __syncthreads();
    s = a; d = b;
    for (int off = 1; off < NB; off <<= 1) {
        for (int i = t; i < NB; i += 1024)
            d[i] = s[i] + (i >= off ? s[i - off] : 0u);
        __syncthreads();
        unsigned* tmp = s; s = d; d = tmp;
    }
    for (int i = t; i < NB; i += 1024) {
        unsigned ex = (i == 0) ? 0u : s[i - 1];
        startS[i] = ex; cursorS[i] = ex;
    }
    if (t == 0) startS[NB] = s[NB - 1];
}

__global__ __launch_bounds__(256) void k_place(const int* __restrict__ ei, int E, int NB,
                                               unsigned* __restrict__ cursorD,
                                               unsigned* __restrict__ cursorS,
                                               unsigned* __restrict__ dstbin,
                                               unsigned char* __restrict__ srcbin) {
    __shared__ unsigned hD[MAXNB], hS[MAXNB], bD[MAXNB], bS[MAXNB];
    int t = threadIdx.x;
    for (int i = t; i < NB; i += 256) { hD[i] = 0u; hS[i] = 0u; }
    __syncthreads();
    int e0 = blockIdx.x * EPB, e1 = min(e0 + EPB, E);
    for (int e = e0 + t; e < e1; e += 256) {
        int s = ei[e], d = ei[E + e];
        if (s != d) {
            atomicAdd(&hD[d >> BSH], 1u);
            atomicAdd(&hS[s >> BSH], 1u);
        }
    }
    __syncthreads();
    for (int i = t; i < NB; i += 256) {
        unsigned h = hD[i];
        bD[i] = h ? atomicAdd(&cursorD[i], h) : 0u;
        h = hS[i];
        bS[i] = h ? atomicAdd(&cursorS[i], h) : 0u;
        hD[i] = 0u; hS[i] = 0u;
    }
    __syncthreads();
    for (int e = e0 + t; e < e1; e += 256) {
        int s = ei[e], d = ei[E + e];
        if (s != d) {
            int bk = d >> BSH;
            unsigned pos = bD[bk] + atomicAdd(&hD[bk], 1u);
            dstbin[pos] = ((unsigned)(d & (BSZ - 1)) << SRC_BITS) | (unsigned)s;
            int bs = s >> BSH;
            unsigned ps = bS[bs] + atomicAdd(&hS[bs], 1u);
            srcbin[ps] = (unsigned char)(s & (BSZ - 1));
        }
    }
}

__global__ __launch_bounds__(256) void k_deginv(const unsigned char* __restrict__ srcbin,
                                                const unsigned* __restrict__ startS,
                                                float* __restrict__ dinv, int N) {
    __shared__ unsigned cnt[4][BSZ];
    int t = threadIdx.x, b = blockIdx.x;
    for (int i = t; i < 4 * BSZ; i += 256) ((unsigned*)cnt)[i] = 0u;
    __syncthreads();
    unsigned i0 = startS[b], i1 = startS[b + 1];
    int rep = t & 3;
    for (unsigned i = i0 + t; i < i1; i += 256) atomicAdd(&cnt[rep][srcbin[i]], 1u);
    __syncthreads();
    int g = b * BSZ + t;
    if (t < BSZ && g < N) {
        unsigned c = cnt[0][t] + cnt[1][t] + cnt[2][t] + cnt[3][t];
        dinv[g] = c ? rsqrtf((float)c) : 0.f;
    }
}

// 4 lanes per node, shfl_xor reduce. 64 nodes / 256-thread block.
__global__ __launch_bounds__(256) void k_gemm1(
    const float* __restrict__ x, const float* __restrict__ W0a,
    const float* __restrict__ W1a, const float* __restrict__ dinv,
    float4* __restrict__ a3v, float4* __restrict__ y3v, int n) {
    __shared__ float w0[192], w1[192];
    int t = threadIdx.x;
    if (t < 192) { w0[t] = W0a[t]; w1[t] = W1a[t]; }
    __syncthreads();
    int q = t & 3, nn = t >> 2;
    int node = blockIdx.x * 64 + nn;
    float acc[6] = {0.f, 0.f, 0.f, 0.f, 0.f, 0.f};
    if (node < n) {
        const float4* xr = (const float4*)(x + (size_t)node * 64 + q * 16);
#pragma unroll
        for (int i = 0; i < 4; i++) {
            float4 v = xr[i];
            float xs[4] = {v.x, v.y, v.z, v.w};
#pragma unroll
            for (int c = 0; c < 4; c++) {
                int f = q * 16 + i * 4 + c;
                float xi = xs[c];
                acc[0] += xi * w0[f * 3 + 0];
                acc[1] += xi * w0[f * 3 + 1];
                acc[2] += xi * w0[f * 3 + 2];
                acc[3] += xi * w1[f * 3 + 0];
                acc[4] += xi * w1[f * 3 + 1];
                acc[5] += xi * w1[f * 3 + 2];
            }
        }
    }
#pragma unroll
    for (int m = 1; m < 4; m <<= 1)
#pragma unroll
        for (int j = 0; j < 6; j++) acc[j] += __shfl_xor(acc[j], m, 64);
    if (q == 0 && node < n) {
        a3v[node] = make_float4(acc[0], acc[1], acc[2], 0.f);
        y3v[node] = make_float4(acc[3], acc[4], acc[5], dinv[node]);
    }
}

// One block per dst-bucket, 4-way replicated LDS accumulators.
__global__ __launch_bounds__(256) void k_tgather(const unsigned* __restrict__ dstbin,
                                                 const unsigned* __restrict__ startD,
                                                 const float4* __restrict__ v4,
                                                 const float* __restrict__ dinv,
                                                 const float4* __restrict__ a3v,
                                                 const float* __restrict__ b1,
                                                 float4* __restrict__ outv, int N,
                                                 int phase) {
    __shared__ float acc[4][BSZ][4];
    __shared__ float dl[BSZ];
    int t = threadIdx.x, b = blockIdx.x;
    for (int i = t; i < 4 * BSZ * 4; i += 256) ((float*)acc)[i] = 0.f;
    if (t < BSZ) {
        int g = b * BSZ + t;
        dl[t] = (g < N) ? dinv[g] : 0.f;
    }
    __syncthreads();
    int rep = t & 3;
    unsigned i0 = startD[b], i1 = startD[b + 1];
    for (unsigned i = i0 + t; i < i1; i += 256) {
        unsigned p = dstbin[i];
        int s = (int)(p & SRC_MASK);
        int di = (int)(p >> SRC_BITS);
        float4 v = v4[s];
        float nm = -v.w * dl[di];
        if (nm != 0.f) {
            atomicAdd(&acc[rep][di][0], nm * v.x);
            atomicAdd(&acc[rep][di][1], nm * v.y);
            atomicAdd(&acc[rep][di][2], nm * v.z);
        }
    }
    __syncthreads();
    if (t < BSZ) {
        int g = b * BSZ + t;
        if (g < N) {
            float s0 = acc[0][t][0] + acc[1][t][0] + acc[2][t][0] + acc[3][t][0];
            float s1 = acc[0][t][1] + acc[1][t][1] + acc[2][t][1] + acc[3][t][1];
            float s2 = acc[0][t][2] + acc[1][t][2] + acc[2][t][2] + acc[3][t][2];
            if (phase == 1) {
                float4 a = a3v[g];
                outv[g] = make_float4(fmaxf(s0 + a.x + b1[0], 0.f),
                                      fmaxf(s1 + a.y + b1[1], 0.f),
                                      fmaxf(s2 + a.z + b1[2], 0.f), dl[t]);
            } else {
                outv[g] = make_float4(s0, s1, s2, 0.f);
            }
        }
    }
}

// WlT[c][k] = bf16(Wl[k][c]); Wl is [256][512] f32.
__global__ __launch_bounds__(256) void k_prep(const float* __restrict__ Wl,
                                              unsigned short* __restrict__ WlT) {
    __shared__ float tile[32][33];
    int t = threadIdx.x, tx = t & 31, ty = t >> 5;
    int kb = (blockIdx.x & 7) * 32;
    int cb = (blockIdx.x >> 3) * 32;
#pragma unroll
    for (int r = 0; r < 4; r++) {
        int k = kb + ty + r * 8;
        tile[ty + r * 8][tx] = Wl[(size_t)k * 512 + cb + tx];
    }
    __syncthreads();
#pragma unroll
    for (int r = 0; r < 4; r++) {
        int c = cb + ty + r * 8;
        WlT[(size_t)c * 256 + kb + tx] = f2bf(tile[tx][ty + r * 8]);
    }
}

// 128 nodes/block, 512 threads (8 waves), wave w -> rows (w&1)*64, cols (w>>1)*128.
// Phase 1: h2[128][256] bf16 into XOR-swizzled LDS (byte ^= (row&7)<<4).
// Phase 2: MFMA 16x16x32 bf16, A from LDS, B from WlT (L2), + bl, store f32.
__global__ __launch_bounds__(512) void k_final_mfma(
    const float4* __restrict__ h1v, const float4* __restrict__ t2r,
    const float* __restrict__ W0b, const float* __restrict__ W1b,
    const float* __restrict__ b2, const unsigned short* __restrict__ WlT,
    const float* __restrict__ bl, float* __restrict__ out, int N) {
    __shared__ unsigned short h2s[128 * 256];  // 64 KB
    __shared__ float4 u4[128][2];              // 4 KB [h1 | t2]
    char* h2b = (char*)h2s;
    int t = threadIdx.x;
    int n0 = blockIdx.x * 128;

    if (t < 128) {
        int g = n0 + t;
        u4[t][0] = (g < N) ? h1v[g] : make_float4(0.f, 0.f, 0.f, 0.f);
    } else if (t < 256) {
        int g = n0 + t - 128;
        u4[t - 128][1] = (g < N) ? t2r[g] : make_float4(0.f, 0.f, 0.f, 0.f);
    }
    __syncthreads();

    {   // phase 1: thread handles cols k0,k0+1 for 32 rows
        int k0 = (t & 127) * 2;
        int rh = (t >> 7) * 32;
        float w00a = W0b[k0],       w00b = W0b[k0 + 1];
        float w01a = W0b[256 + k0], w01b = W0b[256 + k0 + 1];
        float w02a = W0b[512 + k0], w02b = W0b[512 + k0 + 1];
        float w10a = W1b[k0],       w10b = W1b[k0 + 1];
        float w11a = W1b[256 + k0], w11b = W1b[256 + k0 + 1];
        float w12a = W1b[512 + k0], w12b = W1b[512 + k0 + 1];
        float bka = b2[k0], bkb = b2[k0 + 1];
        int kbyte = k0 * 2;
#pragma unroll
        for (int r = 0; r < 32; r++) {
            int rr = rh + r;
            float4 h = u4[rr][0];
            float4 v = u4[rr][1];
            float za = bka + h.x * w00a + h.y * w01a + h.z * w02a
                           + v.x * w10a + v.y * w11a + v.z * w12a;
            float zb = bkb + h.x * w00b + h.y * w01b + h.z * w02b
                           + v.x * w10b + v.y * w11b + v.z * w12b;
            za = fmaxf(za, 0.f); zb = fmaxf(zb, 0.f);
            unsigned pk = ((unsigned)f2bf(zb) << 16) | (unsigned)f2bf(za);
            int byte = rr * 512 + (kbyte ^ ((rr & 7) << 4));
            *(unsigned*)(h2b + byte) = pk;
        }
    }
    __syncthreads();

    // phase 2: wave w -> rows (w&1)*64, cols (w>>1)*128  (full 128x512 coverage)
    int w = t >> 6, l = t & 63;
    int row0 = (w & 1) * 64, col0 = (w >> 1) * 128;
    int lrow = l & 15, lkb = (l >> 4) * 8;
    f32x4 acc[4][8];
#pragma unroll
    for (int rt = 0; rt < 4; rt++)
#pragma unroll
        for (int ct = 0; ct < 8; ct++) acc[rt][ct] = (f32x4)0.f;

#pragma unroll
    for (int ks = 0; ks < 8; ks++) {
        int kel = ks * 32 + lkb;
        short8 af[4];
#pragma unroll
        for (int rt = 0; rt < 4; rt++) {
            int r = row0 + rt * 16 + lrow;
            int byte = r * 512 + ((kel * 2) ^ ((r & 7) << 4));
            af[rt] = *(const short8*)(h2b + byte);
        }
        short8 bf[8];
#pragma unroll
        for (int ct = 0; ct < 8; ct++) {
            int c = col0 + ct * 16 + lrow;
            bf[ct] = *(const short8*)(WlT + (size_t)c * 256 + kel);
        }
#pragma unroll
        for (int rt = 0; rt < 4; rt++)
#pragma unroll
            for (int ct = 0; ct < 8; ct++)
                acc[rt][ct] = __builtin_amdgcn_mfma_f32_16x16x32_bf16(
                    af[rt], bf[ct], acc[rt][ct], 0, 0, 0);
    }

    float blv[8];
#pragma unroll
    for (int ct = 0; ct < 8; ct++) blv[ct] = bl[col0 + ct * 16 + lrow];
#pragma unroll
    for (int rt = 0; rt < 4; rt++) {
        int rbase = n0 + row0 + rt * 16 + (l >> 4) * 4;
#pragma unroll
        for (int j = 0; j < 4; j++) {
            int row = rbase + j;
            if (row < N) {
                float* orow = out + (size_t)row * 512 + col0 + lrow;
#pragma unroll
                for (int ct = 0; ct < 8; ct++)
                    orow[ct * 16] = acc[rt][ct][j] + blv[ct];
            }
        }
    }
}

extern "C" void kernel_launch(void* const* d_in, const int* in_sizes, int n_in,
                              void* d_out, int out_size, void* d_ws, size_t ws_size,
                              hipStream_t stream) {
    const float* x   = (const float*)d_in[0];
    const int*   ei  = (const int*)d_in[1];
    const float* W0a = (const float*)d_in[2];
    const float* W1a = (const float*)d_in[3];
    const float* b1  = (const float*)d_in[4];
    const float* W0b = (const float*)d_in[5];
    const float* W1b = (const float*)d_in[6];
    const float* b2  = (const float*)d_in[7];
    const float* Wl  = (const float*)d_in[8];
    const float* bl  = (const float*)d_in[9];
    float* out = (float*)d_out;

    const int N = in_sizes[0] / 64;
    const int E = in_sizes[1] / 2;
    const int NB = (N + BSZ - 1) >> BSH;

    char* base = (char*)d_ws;
    size_t off = 0;
    auto alloc = [&](size_t bytes) {
        void* p = base + off;
        off = (off + bytes + 255) & ~(size_t)255;
        return p;
    };
    unsigned* ghistD  = (unsigned*)alloc(MAXNB * 4);
    unsigned* ghistS  = (unsigned*)alloc(MAXNB * 4);
    unsigned* startD  = (unsigned*)alloc((MAXNB + 1) * 4);
    unsigned* startS  = (unsigned*)alloc((MAXNB + 1) * 4);
    unsigned* cursorD = (unsigned*)alloc(MAXNB * 4);
    unsigned* cursorS = (unsigned*)alloc(MAXNB * 4);
    unsigned* dstbin  = (unsigned*)alloc((size_t)E * 4);
    unsigned char* srcbin = (unsigned char*)alloc((size_t)E);
    float* dinv = (float*)alloc((size_t)N * 4);
    float* a3v  = (float*)alloc((size_t)N * 16);
    float* y3v  = (float*)alloc((size_t)N * 16);
    float* h1v  = (float*)alloc((size_t)N * 16);
    float* t2r  = (float*)alloc((size_t)N * 16);
    unsigned short* WlT = (unsigned short*)alloc(512 * 256 * 2);

    hipMemsetAsync(ghistD, 0, MAXNB * 4, stream);
    hipMemsetAsync(ghistS, 0, MAXNB * 4, stream);

    const int CB = (E + EPB - 1) / EPB;

    k_prep<<<128, 256, 0, stream>>>(Wl, WlT);
    k_hist<<<CB, 256, 0, stream>>>(ei, E, NB, ghistD, ghistS);
    k_scan<<<1, 1024, 0, stream>>>(ghistD, ghistS, startD, startS, cursorD, cursorS, NB);
    k_place<<<CB, 256, 0, stream>>>(ei, E, NB, cursorD, cursorS, dstbin, srcbin);
    k_deginv<<<NB, 256, 0, stream>>>(srcbin, startS, dinv, N);
    k_gemm1<<<(N + 63) / 64, 256, 0, stream>>>(x, W0a, W1a, dinv,
                                               (float4*)a3v, (float4*)y3v, N);
    k_tgather<<<NB, 256, 0, stream>>>(dstbin, startD, (const float4*)y3v, dinv,
                                      (const float4*)a3v, b1, (float4*)h1v, N, 1);
    k_tgather<<<NB, 256, 0, stream>>>(dstbin, startD, (const float4*)h1v, dinv,
                                      (const float4*)a3v, b1, (float4*)t2r, N, 2);
    k_final_mfma<<<(N + 127) / 128, 512, 0, stream>>>(
        (const float4*)h1v, (const float4*)t2r, W0b, W1b, b2, WlT, bl, out, N);
}

// Round 7
// 338.808 us; speedup vs baseline: 4.3350x; 1.0717x over previous
//
#include <hip/hip_runtime.h>
#include <hip/hip_bf16.h>

// Pipeline (9 graph nodes):
//  0. memset: subcurD|subcurS (8 KB)
//  1. k_prep : WlT[512][256] bf16 = transpose(Wl)
//  2. k_hist : per-block LDS hist of dst/src buckets; flush reserves sub-ranges
//              via atomicAdd(subcur) and records per-(block,bucket) base table
//  3. k_scan : exclusive scan of subcur totals -> bucket start offsets
//  4. k_place: single pass over ei; pos = start[bk] + base[blk][bk] + LDS intra
//  5. k_deggemm: per src-bucket count -> dinv; fused a3 = x@W0a, y3 = x@W1a
//  6. k_tgather(P1): per dst-bucket LDS accumulate t1 (acc[4][3][128], bank=di%32),
//     fuse h1 = relu(a3+t1+b1), h1.w = dinv
//  7. k_tgather(P2): same for t2
//  8. k_final_mfma: 128 rows/block, 8 waves x (64x128), h2 -> bf16 XOR-swizzled LDS;
//     out = h2@Wl + bl via mfma_f32_16x16x32_bf16

#define MAXNB 1024
#define BSH 7
#define BSZ 128
#define SRC_BITS 20
#define SRC_MASK ((1u << SRC_BITS) - 1u)
#define EPB 16384

typedef __attribute__((ext_vector_type(8))) short short8;
typedef __attribute__((ext_vector_type(4))) float f32x4;

static __device__ inline unsigned short f2bf(float f) {
    union { float f; unsigned u; } v; v.f = f;
    unsigned r = (v.u + 0x7fffu + ((v.u >> 16) & 1u)) >> 16;
    return (unsigned short)r;
}

// LDS hist + single atomic reserve; base tables let k_place run atomic-free (global).
__global__ __launch_bounds__(256) void k_hist(const int* __restrict__ ei, int E, int NB,
                                              unsigned* __restrict__ subcurD,
                                              unsigned* __restrict__ subcurS,
                                              unsigned* __restrict__ baseD,
                                              unsigned* __restrict__ baseS) {
    __shared__ unsigned hD[MAXNB], hS[MAXNB];
    int t = threadIdx.x, blk = blockIdx.x;
    for (int i = t; i < NB; i += 256) { hD[i] = 0u; hS[i] = 0u; }
    __syncthreads();
    int e0 = blk * EPB, e1 = min(e0 + EPB, E);
    for (int e = e0 + t; e < e1; e += 256) {
        int s = ei[e], d = ei[E + e];
        if (s != d) {
            atomicAdd(&hD[d >> BSH], 1u);
            atomicAdd(&hS[s >> BSH], 1u);
        }
    }
    __syncthreads();
    unsigned* bD = baseD + (size_t)blk * NB;
    unsigned* bS = baseS + (size_t)blk * NB;
    for (int i = t; i < NB; i += 256) {
        unsigned h = hD[i];
        if (h) bD[i] = atomicAdd(&subcurD[i], h);
        h = hS[i];
        if (h) bS[i] = atomicAdd(&subcurS[i], h);
    }
}

__global__ __launch_bounds__(1024) void k_scan(const unsigned* __restrict__ totD,
                                               const unsigned* __restrict__ totS,
                                               unsigned* __restrict__ startD,
                                               unsigned* __restrict__ startS, int NB) {
    __shared__ unsigned a[MAXNB], b[MAXNB];
    int t = threadIdx.x;
    for (int i = t; i < NB; i += 1024) a[i] = totD[i];
    __syncthreads();
    unsigned* s = a; unsigned* d = b;
    for (int off = 1; off < NB; off <<= 1) {
        for (int i = t; i < NB; i += 1024)
            d[i] = s[i] + (i >= off ? s[i - off] : 0u);
        __syncthreads();
        unsigned* tmp = s; s = d; d = tmp;
    }
    for (int i = t; i < NB; i += 1024)
        startD[i] = (i == 0) ? 0u : s[i - 1];
    if (t == 0) startD[NB] = s[NB - 1];
    __syncthreads();
    for (int i = t; i < NB; i += 1024) a[i] = totS[i];
    __syncthreads();
    s = a; d = b;
    for (int off = 1; off < NB; off <<= 1) {
        for (int i = t; i < NB; i += 1024)
            d[i] = s[i] + (i >= off ? s[i - off] : 0u);
        __syncthreads();
        unsigned* tmp = s; s = d; d = tmp;
    }
    for (int i = t; i < NB; i += 1024)
        startS[i] = (i == 0) ? 0u : s[i - 1];
    if (t == 0) startS[NB] = s[NB - 1];
}

// Single pass over ei: LDS offsets = start + base, LDS intra-block cursors.
__global__ __launch_bounds__(256) void k_place(const int* __restrict__ ei, int E, int NB,
                                               const unsigned* __restrict__ startD,
                                               const unsigned* __restrict__ startS,
                                               const unsigned* __restrict__ baseD,
                                               const unsigned* __restrict__ baseS,
                                               unsigned* __restrict__ dstbin,
                                               unsigned char* __restrict__ srcbin) {
    __shared__ unsigned oD[MAXNB], oS[MAXNB], cD[MAXNB], cS[MAXNB];
    int t = threadIdx.x, blk = blockIdx.x;
    const unsigned* bD = baseD + (size_t)blk * NB;
    const unsigned* bS = baseS + (size_t)blk * NB;
    for (int i = t; i < NB; i += 256) {
        oD[i] = startD[i] + bD[i];   // bD poison only if bucket empty in this block -> unused
        oS[i] = startS[i] + bS[i];
        cD[i] = 0u; cS[i] = 0u;
    }
    __syncthreads();
    int e0 = blk * EPB, e1 = min(e0 + EPB, E);
    for (int e = e0 + t; e < e1; e += 256) {
        int s = ei[e], d = ei[E + e];
        if (s != d) {
            int bk = d >> BSH;
            unsigned pos = oD[bk] + atomicAdd(&cD[bk], 1u);
            dstbin[pos] = ((unsigned)(d & (BSZ - 1)) << SRC_BITS) | (unsigned)s;
            int bs = s >> BSH;
            unsigned ps = oS[bs] + atomicAdd(&cS[bs], 1u);
            srcbin[ps] = (unsigned char)(s & (BSZ - 1));
        }
    }
}

// Fused: per src-bucket degree count -> dinv, then 128-node [64->3,3] gemm.
__global__ __launch_bounds__(256) void k_deggemm(
    const unsigned char* __restrict__ srcbin, const unsigned* __restrict__ startS,
    const float* __restrict__ x, const float* __restrict__ W0a,
    const float* __restrict__ W1a, float* __restrict__ dinv,
    float4* __restrict__ a3v, float4* __restrict__ y3v, int N) {
    __shared__ unsigned cnt[4][BSZ];
    __shared__ float w0[192], w1[192];
    __shared__ float dl[BSZ];
    int t = threadIdx.x, b = blockIdx.x;
    if (t < 192) { w0[t] = W0a[t]; w1[t] = W1a[t]; }
    for (int i = t; i < 4 * BSZ; i += 256) ((unsigned*)cnt)[i] = 0u;
    __syncthreads();
    unsigned i0 = startS[b], i1 = startS[b + 1];
    int rep = t & 3;
    for (unsigned i = i0 + t; i < i1; i += 256) atomicAdd(&cnt[rep][srcbin[i]], 1u);
    __syncthreads();
    if (t < BSZ) {
        unsigned c = cnt[0][t] + cnt[1][t] + cnt[2][t] + cnt[3][t];
        float dv = c ? rsqrtf((float)c) : 0.f;
        dl[t] = dv;
        int g = b * BSZ + t;
        if (g < N) dinv[g] = dv;
    }
    __syncthreads();
    int q = t & 3;
#pragma unroll
    for (int pass = 0; pass < 2; pass++) {
        int nn = (t >> 2) + pass * 64;
        int node = b * BSZ + nn;
        float acc[6] = {0.f, 0.f, 0.f, 0.f, 0.f, 0.f};
        if (node < N) {
            const float4* xr = (const float4*)(x + (size_t)node * 64 + q * 16);
#pragma unroll
            for (int i = 0; i < 4; i++) {
                float4 v = xr[i];
                float xs[4] = {v.x, v.y, v.z, v.w};
#pragma unroll
                for (int c = 0; c < 4; c++) {
                    int f = q * 16 + i * 4 + c;
                    float xi = xs[c];
                    acc[0] += xi * w0[f * 3 + 0];
                    acc[1] += xi * w0[f * 3 + 1];
                    acc[2] += xi * w0[f * 3 + 2];
                    acc[3] += xi * w1[f * 3 + 0];
                    acc[4] += xi * w1[f * 3 + 1];
                    acc[5] += xi * w1[f * 3 + 2];
                }
            }
        }
#pragma unroll
        for (int m = 1; m < 4; m <<= 1)
#pragma unroll
            for (int j = 0; j < 6; j++) acc[j] += __shfl_xor(acc[j], m, 64);
        if (q == 0 && node < N) {
            a3v[node] = make_float4(acc[0], acc[1], acc[2], 0.f);
            y3v[node] = make_float4(acc[3], acc[4], acc[5], dl[nn]);
        }
    }
}

// One block per dst-bucket. acc[rep][c][di]: bank = di%32 (full spread).
__global__ __launch_bounds__(256) void k_tgather(const unsigned* __restrict__ dstbin,
                                                 const unsigned* __restrict__ startD,
                                                 const float4* __restrict__ v4,
                                                 const float* __restrict__ dinv,
                                                 const float4* __restrict__ a3v,
                                                 const float* __restrict__ b1,
                                                 float4* __restrict__ outv, int N,
                                                 int phase) {
    __shared__ float acc[4][3][BSZ];
    __shared__ float dl[BSZ];
    int t = threadIdx.x, b = blockIdx.x;
    for (int i = t; i < 4 * 3 * BSZ; i += 256) ((float*)acc)[i] = 0.f;
    if (t < BSZ) {
        int g = b * BSZ + t;
        dl[t] = (g < N) ? dinv[g] : 0.f;
    }
    __syncthreads();
    int rep = t & 3;
    unsigned i0 = startD[b], i1 = startD[b + 1];
    for (unsigned i = i0 + t; i < i1; i += 256) {
        unsigned p = dstbin[i];
        int s = (int)(p & SRC_MASK);
        int di = (int)(p >> SRC_BITS);
        float4 v = v4[s];
        float nm = -v.w * dl[di];
        if (nm != 0.f) {
            atomicAdd(&acc[rep][0][di], nm * v.x);
            atomicAdd(&acc[rep][1][di], nm * v.y);
            atomicAdd(&acc[rep][2][di], nm * v.z);
        }
    }
    __syncthreads();
    if (t < BSZ) {
        int g = b * BSZ + t;
        if (g < N) {
            float s0 = acc[0][0][t] + acc[1][0][t] + acc[2][0][t] + acc[3][0][t];
            float s1 = acc[0][1][t] + acc[1][1][t] + acc[2][1][t] + acc[3][1][t];
            float s2 = acc[0][2][t] + acc[1][2][t] + acc[2][2][t] + acc[3][2][t];
            if (phase == 1) {
                float4 a = a3v[g];
                outv[g] = make_float4(fmaxf(s0 + a.x + b1[0], 0.f),
                                      fmaxf(s1 + a.y + b1[1], 0.f),
                                      fmaxf(s2 + a.z + b1[2], 0.f), dl[t]);
            } else {
                outv[g] = make_float4(s0, s1, s2, 0.f);
            }
        }
    }
}

// WlT[c][k] = bf16(Wl[k][c]); Wl is [256][512] f32.
__global__ __launch_bounds__(256) void k_prep(const float* __restrict__ Wl,
                                              unsigned short* __restrict__ WlT) {
    __shared__ float tile[32][33];
    int t = threadIdx.x, tx = t & 31, ty = t >> 5;
    int kb = (blockIdx.x & 7) * 32;
    int cb = (blockIdx.x >> 3) * 32;
#pragma unroll
    for (int r = 0; r < 4; r++) {
        int k = kb + ty + r * 8;
        tile[ty + r * 8][tx] = Wl[(size_t)k * 512 + cb + tx];
    }
    __syncthreads();
#pragma unroll
    for (int r = 0; r < 4; r++) {
        int c = cb + ty + r * 8;
        WlT[(size_t)c * 256 + kb + tx] = f2bf(tile[tx][ty + r * 8]);
    }
}

// 128 nodes/block, 512 threads (8 waves), wave w -> rows (w&1)*64, cols (w>>1)*128.
__global__ __launch_bounds__(512) void k_final_mfma(
    const float4* __restrict__ h1v, const float4* __restrict__ t2r,
    const float* __restrict__ W0b, const float* __restrict__ W1b,
    const float* __restrict__ b2, const unsigned short* __restrict__ WlT,
    const float* __restrict__ bl, float* __restrict__ out, int N) {
    __shared__ unsigned short h2s[128 * 256];  // 64 KB
    __shared__ float4 u4[128][2];
    char* h2b = (char*)h2s;
    int t = threadIdx.x;
    int n0 = blockIdx.x * 128;

    if (t < 128) {
        int g = n0 + t;
        u4[t][0] = (g < N) ? h1v[g] : make_float4(0.f, 0.f, 0.f, 0.f);
    } else if (t < 256) {
        int g = n0 + t - 128;
        u4[t - 128][1] = (g < N) ? t2r[g] : make_float4(0.f, 0.f, 0.f, 0.f);
    }
    __syncthreads();

    {   // phase 1
        int k0 = (t & 127) * 2;
        int rh = (t >> 7) * 32;
        float w00a = W0b[k0],       w00b = W0b[k0 + 1];
        float w01a = W0b[256 + k0], w01b = W0b[256 + k0 + 1];
        float w02a = W0b[512 + k0], w02b = W0b[512 + k0 + 1];
        float w10a = W1b[k0],       w10b = W1b[k0 + 1];
        float w11a = W1b[256 + k0], w11b = W1b[256 + k0 + 1];
        float w12a = W1b[512 + k0], w12b = W1b[512 + k0 + 1];
        float bka = b2[k0], bkb = b2[k0 + 1];
        int kbyte = k0 * 2;
#pragma unroll
        for (int r = 0; r < 32; r++) {
            int rr = rh + r;
            float4 h = u4[rr][0];
            float4 v = u4[rr][1];
            float za = bka + h.x * w00a + h.y * w01a + h.z * w02a
                           + v.x * w10a + v.y * w11a + v.z * w12a;
            float zb = bkb + h.x * w00b + h.y * w01b + h.z * w02b
                           + v.x * w10b + v.y * w11b + v.z * w12b;
            za = fmaxf(za, 0.f); zb = fmaxf(zb, 0.f);
            unsigned pk = ((unsigned)f2bf(zb) << 16) | (unsigned)f2bf(za);
            int byte = rr * 512 + (kbyte ^ ((rr & 7) << 4));
            *(unsigned*)(h2b + byte) = pk;
        }
    }
    __syncthreads();

    // phase 2
    int w = t >> 6, l = t & 63;
    int row0 = (w & 1) * 64, col0 = (w >> 1) * 128;
    int lrow = l & 15, lkb = (l >> 4) * 8;
    f32x4 acc[4][8];
#pragma unroll
    for (int rt = 0; rt < 4; rt++)
#pragma unroll
        for (int ct = 0; ct < 8; ct++) acc[rt][ct] = (f32x4)0.f;

#pragma unroll
    for (int ks = 0; ks < 8; ks++) {
        int kel = ks * 32 + lkb;
        short8 af[4];
#pragma unroll
        for (int rt = 0; rt < 4; rt++) {
            int r = row0 + rt * 16 + lrow;
            int byte = r * 512 + ((kel * 2) ^ ((r & 7) << 4));
            af[rt] = *(const short8*)(h2b + byte);
        }
        short8 bf[8];
#pragma unroll
        for (int ct = 0; ct < 8; ct++) {
            int c = col0 + ct * 16 + lrow;
            bf[ct] = *(const short8*)(WlT + (size_t)c * 256 + kel);
        }
#pragma unroll
        for (int rt = 0; rt < 4; rt++)
#pragma unroll
            for (int ct = 0; ct < 8; ct++)
                acc[rt][ct] = __builtin_amdgcn_mfma_f32_16x16x32_bf16(
                    af[rt], bf[ct], acc[rt][ct], 0, 0, 0);
    }

    float blv[8];
#pragma unroll
    for (int ct = 0; ct < 8; ct++) blv[ct] = bl[col0 + ct * 16 + lrow];
#pragma unroll
    for (int rt = 0; rt < 4; rt++) {
        int rbase = n0 + row0 + rt * 16 + (l >> 4) * 4;
#pragma unroll
        for (int j = 0; j < 4; j++) {
            int row = rbase + j;
            if (row < N) {
                float* orow = out + (size_t)row * 512 + col0 + lrow;
#pragma unroll
                for (int ct = 0; ct < 8; ct++)
                    orow[ct * 16] = acc[rt][ct][j] + blv[ct];
            }
        }
    }
}

extern "C" void kernel_launch(void* const* d_in, const int* in_sizes, int n_in,
                              void* d_out, int out_size, void* d_ws, size_t ws_size,
                              hipStream_t stream) {
    const float* x   = (const float*)d_in[0];
    const int*   ei  = (const int*)d_in[1];
    const float* W0a = (const float*)d_in[2];
    const float* W1a = (const float*)d_in[3];
    const float* b1  = (const float*)d_in[4];
    const float* W0b = (const float*)d_in[5];
    const float* W1b = (const float*)d_in[6];
    const float* b2  = (const float*)d_in[7];
    const float* Wl  = (const float*)d_in[8];
    const float* bl  = (const float*)d_in[9];
    float* out = (float*)d_out;

    const int N = in_sizes[0] / 64;
    const int E = in_sizes[1] / 2;
    const int NB = (N + BSZ - 1) >> BSH;
    const int CB = (E + EPB - 1) / EPB;

    char* base = (char*)d_ws;
    size_t off = 0;
    auto alloc = [&](size_t bytes) {
        void* p = base + off;
        off = (off + bytes + 255) & ~(size_t)255;
        return p;
    };
    unsigned* subcurD = (unsigned*)alloc(MAXNB * 4);   // contiguous with subcurS
    unsigned* subcurS = (unsigned*)alloc(MAXNB * 4);
    unsigned* startD  = (unsigned*)alloc((MAXNB + 1) * 4);
    unsigned* startS  = (unsigned*)alloc((MAXNB + 1) * 4);
    unsigned* baseD   = (unsigned*)alloc((size_t)CB * NB * 4);
    unsigned* baseS   = (unsigned*)alloc((size_t)CB * NB * 4);
    unsigned* dstbin  = (unsigned*)alloc((size_t)E * 4);
    unsigned char* srcbin = (unsigned char*)alloc((size_t)E);
    float* dinv = (float*)alloc((size_t)N * 4);
    float* a3v  = (float*)alloc((size_t)N * 16);
    float* y3v  = (float*)alloc((size_t)N * 16);
    float* h1v  = (float*)alloc((size_t)N * 16);
    float* t2r  = (float*)alloc((size_t)N * 16);
    unsigned short* WlT = (unsigned short*)alloc(512 * 256 * 2);

    hipMemsetAsync(subcurD, 0, 2 * MAXNB * 4, stream);  // subcurD + subcurS

    k_prep<<<128, 256, 0, stream>>>(Wl, WlT);
    k_hist<<<CB, 256, 0, stream>>>(ei, E, NB, subcurD, subcurS, baseD, baseS);
    k_scan<<<1, 1024, 0, stream>>>(subcurD, subcurS, startD, startS, NB);
    k_place<<<CB, 256, 0, stream>>>(ei, E, NB, startD, startS, baseD, baseS,
                                    dstbin, srcbin);
    k_deggemm<<<NB, 256, 0, stream>>>(srcbin, startS, x, W0a, W1a, dinv,
                                      (float4*)a3v, (float4*)y3v, N);
    k_tgather<<<NB, 256, 0, stream>>>(dstbin, startD, (const float4*)y3v, dinv,
                                      (const float4*)a3v, b1, (float4*)h1v, N, 1);
    k_tgather<<<NB, 256, 0, stream>>>(dstbin, startD, (const float4*)h1v, dinv,
                                      (const float4*)a3v, b1, (float4*)t2r, N, 2);
    k_final_mfma<<<(N + 127) / 128, 512, 0, stream>>>(
        (const float4*)h1v, (const float4*)t2r, W0b, W1b, b2, WlT, bl, out, N);
}

// Round 8
// 337.798 us; speedup vs baseline: 4.3480x; 1.0030x over previous
//
#include <hip/hip_runtime.h>
#include <hip/hip_bf16.h>

// Pipeline (5 graph nodes, no memsets, no global atomics):
//  1. k_prep     : WlT[512][256] bf16 = transpose(Wl)
//  2. k_sortlocal: each block counting-sorts its 16K-edge slice in LDS by
//                  dst-bucket (payload dlow<<20|src) and src-bucket (u8 slow),
//                  writes sorted slice coalesced + per-(blk,bucket) u16 offsets
//  3. k_deggemm  : segmented srcbin count -> dinv; fused a3 = x@W0a, y3 = x@W1a
//  4. k_tgather  : per-bucket segmented gather of t1 (4-way replicated LDS
//                  float atomics), fuse h1 = relu(a3+t1+b1), h1.w = dinv
//  5. k_final    : fused t2 gather (same scheme, v=h1) + h2 = relu(...) ->
//                  bf16 XOR-swizzled LDS; out = h2@Wl + bl via mfma 16x16x32

#define MAXNB 1024
#define BSH 7
#define BSZ 128
#define SRC_BITS 20
#define SRC_MASK ((1u << SRC_BITS) - 1u)
#define SEPB 16384          // edges per sort block
#define CBMAX 256           // max sort blocks (E <= 4.19M)

typedef __attribute__((ext_vector_type(8))) short short8;
typedef __attribute__((ext_vector_type(4))) float f32x4;

static __device__ inline unsigned short f2bf(float f) {
    union { float f; unsigned u; } v; v.f = f;
    unsigned r = (v.u + 0x7fffu + ((v.u >> 16) & 1u)) >> 16;
    return (unsigned short)r;
}

// Build segStart[] and exclusive prefix Pex[] for bucket b from the u16 offset
// table offT[CB][NB+1]; returns total edges for this bucket. All arrays LDS.
__device__ __forceinline__ unsigned seg_setup(
    const unsigned short* __restrict__ offT, int b, int NB, int CB,
    unsigned* __restrict__ segStart, unsigned* __restrict__ Pex,
    unsigned* __restrict__ wk, int nthr) {
    int t = threadIdx.x;
    for (int i = t; i < CBMAX; i += nthr) {
        unsigned c = 0u, st = 0u;
        if (i < CB) {
            const unsigned short* row = offT + (size_t)i * (NB + 1) + b;
            unsigned o0 = row[0], o1 = row[1];
            st = (unsigned)i * SEPB + o0;
            c = o1 - o0;
        }
        segStart[i] = st;
        wk[i] = c;
    }
    __syncthreads();
    unsigned* s0 = wk; unsigned* s1 = Pex;
#pragma unroll
    for (int off = 1; off < CBMAX; off <<= 1) {
        for (int i = t; i < CBMAX; i += nthr)
            s1[i] = s0[i] + (i >= off ? s0[i - off] : 0u);
        __syncthreads();
        unsigned* tmp = s0; s0 = s1; s1 = tmp;
    }
    // CBMAX=256 -> 8 iters -> inclusive scan back in wk (== s0)
    unsigned tot = s0[CB - 1];
    for (int i = t; i < CBMAX; i += nthr)
        Pex[i] = i ? s0[i - 1] : 0u;
    __syncthreads();
    return tot;
}

__device__ __forceinline__ unsigned seg_pos(const unsigned* __restrict__ segStart,
                                            const unsigned* __restrict__ Pex,
                                            unsigned e) {
    int blk = 0;
#pragma unroll
    for (int st = CBMAX >> 1; st > 0; st >>= 1)
        if (Pex[blk + st] <= e) blk += st;
    return segStart[blk] + (e - Pex[blk]);
}

// One pass over ei: LDS hist, LDS scan, LDS counting-sort, coalesced writeout.
__global__ __launch_bounds__(512) void k_sortlocal(
    const int* __restrict__ ei, int E, int NB,
    unsigned* __restrict__ dstbin, unsigned char* __restrict__ srcbin,
    unsigned short* __restrict__ offD, unsigned short* __restrict__ offS) {
    __shared__ unsigned hD[MAXNB], hS[MAXNB], sc[MAXNB];
    __shared__ unsigned curD[MAXNB], curS[MAXNB];
    __shared__ unsigned stageD[SEPB];        // 64 KB
    __shared__ unsigned char stageS[SEPB];   // 16 KB
    __shared__ unsigned totsh;
    int t = threadIdx.x, blk = blockIdx.x;
    for (int i = t; i < NB; i += 512) { hD[i] = 0u; hS[i] = 0u; }
    __syncthreads();
    int e0 = blk * SEPB, e1 = min(e0 + SEPB, E);
    for (int e = e0 + t; e < e1; e += 512) {
        int s = ei[e], d = ei[E + e];
        if (s != d) {
            atomicAdd(&hD[d >> BSH], 1u);
            atomicAdd(&hS[s >> BSH], 1u);
        }
    }
    __syncthreads();
    {   // scan D (buffers hD<->sc), write exclusive offsets
        unsigned* s0 = hD; unsigned* s1 = sc;
        for (int off = 1; off < NB; off <<= 1) {
            for (int i = t; i < NB; i += 512)
                s1[i] = s0[i] + (i >= off ? s0[i - off] : 0u);
            __syncthreads();
            unsigned* tmp = s0; s0 = s1; s1 = tmp;
        }
        unsigned short* row = offD + (size_t)blk * (NB + 1);
        for (int i = t; i < NB; i += 512) {
            unsigned ex = i ? s0[i - 1] : 0u;
            curD[i] = ex;
            row[i] = (unsigned short)ex;
        }
        if (t == 0) { row[NB] = (unsigned short)s0[NB - 1]; totsh = s0[NB - 1]; }
    }
    __syncthreads();
    {   // scan S (buffers hS<->sc)
        unsigned* s0 = hS; unsigned* s1 = sc;
        for (int off = 1; off < NB; off <<= 1) {
            for (int i = t; i < NB; i += 512)
                s1[i] = s0[i] + (i >= off ? s0[i - off] : 0u);
            __syncthreads();
            unsigned* tmp = s0; s0 = s1; s1 = tmp;
        }
        unsigned short* row = offS + (size_t)blk * (NB + 1);
        for (int i = t; i < NB; i += 512) {
            unsigned ex = i ? s0[i - 1] : 0u;
            curS[i] = ex;
            row[i] = (unsigned short)ex;
        }
        if (t == 0) row[NB] = (unsigned short)s0[NB - 1];
    }
    __syncthreads();
    // pass 2: place into LDS staging (ei slice is L2-hot from pass 1)
    for (int e = e0 + t; e < e1; e += 512) {
        int s = ei[e], d = ei[E + e];
        if (s != d) {
            unsigned p = atomicAdd(&curD[d >> BSH], 1u);
            stageD[p] = ((unsigned)(d & (BSZ - 1)) << SRC_BITS) | (unsigned)s;
            unsigned ps = atomicAdd(&curS[s >> BSH], 1u);
            stageS[ps] = (unsigned char)(s & (BSZ - 1));
        }
    }
    __syncthreads();
    unsigned tot = totsh;
    for (unsigned i = t; i < tot; i += 512) dstbin[e0 + i] = stageD[i];
    unsigned tot4 = (tot + 3) >> 2;
    unsigned* srcb4 = (unsigned*)(srcbin + e0);
    for (unsigned i = t; i < tot4; i += 512) srcb4[i] = ((unsigned*)stageS)[i];
}

// Segmented degree count -> dinv; fused 128-node [64->3,3] gemm.
__global__ __launch_bounds__(256) void k_deggemm(
    const unsigned char* __restrict__ srcbin, const unsigned short* __restrict__ offS,
    const float* __restrict__ x, const float* __restrict__ W0a,
    const float* __restrict__ W1a, float* __restrict__ dinv,
    float4* __restrict__ a3v, float4* __restrict__ y3v, int N, int NB, int CB) {
    __shared__ unsigned cnt[4][BSZ];
    __shared__ float w0[192], w1[192];
    __shared__ float dl[BSZ];
    __shared__ unsigned segStart[CBMAX], Pex[CBMAX], wk[CBMAX];
    int t = threadIdx.x, b = blockIdx.x;
    if (t < 192) { w0[t] = W0a[t]; w1[t] = W1a[t]; }
    for (int i = t; i < 4 * BSZ; i += 256) ((unsigned*)cnt)[i] = 0u;
    unsigned tot = seg_setup(offS, b, NB, CB, segStart, Pex, wk, 256);
    int rep = t & 3;
    for (unsigned e = t; e < tot; e += 256)
        atomicAdd(&cnt[rep][srcbin[seg_pos(segStart, Pex, e)]], 1u);
    __syncthreads();
    if (t < BSZ) {
        unsigned c = cnt[0][t] + cnt[1][t] + cnt[2][t] + cnt[3][t];
        float dv = c ? rsqrtf((float)c) : 0.f;
        dl[t] = dv;
        int g = b * BSZ + t;
        if (g < N) dinv[g] = dv;
    }
    __syncthreads();
    int q = t & 3;
#pragma unroll
    for (int pass = 0; pass < 2; pass++) {
        int nn = (t >> 2) + pass * 64;
        int node = b * BSZ + nn;
        float acc[6] = {0.f, 0.f, 0.f, 0.f, 0.f, 0.f};
        if (node < N) {
            const float4* xr = (const float4*)(x + (size_t)node * 64 + q * 16);
#pragma unroll
            for (int i = 0; i < 4; i++) {
                float4 v = xr[i];
                float xs[4] = {v.x, v.y, v.z, v.w};
#pragma unroll
                for (int c = 0; c < 4; c++) {
                    int f = q * 16 + i * 4 + c;
                    float xi = xs[c];
                    acc[0] += xi * w0[f * 3 + 0];
                    acc[1] += xi * w0[f * 3 + 1];
                    acc[2] += xi * w0[f * 3 + 2];
                    acc[3] += xi * w1[f * 3 + 0];
                    acc[4] += xi * w1[f * 3 + 1];
                    acc[5] += xi * w1[f * 3 + 2];
                }
            }
        }
#pragma unroll
        for (int m = 1; m < 4; m <<= 1)
#pragma unroll
            for (int j = 0; j < 6; j++) acc[j] += __shfl_xor(acc[j], m, 64);
        if (q == 0 && node < N) {
            a3v[node] = make_float4(acc[0], acc[1], acc[2], 0.f);
            y3v[node] = make_float4(acc[3], acc[4], acc[5], dl[nn]);
        }
    }
}

// Per-bucket segmented gather of t1; epilogue h1 = relu(a3+t1+b1), h1.w=dinv.
__global__ __launch_bounds__(512) void k_tgather(
    const unsigned* __restrict__ dstbin, const unsigned short* __restrict__ offD,
    const float4* __restrict__ v4, const float* __restrict__ dinv,
    const float4* __restrict__ a3v, const float* __restrict__ b1,
    float4* __restrict__ outv, int N, int NB, int CB) {
    __shared__ float acc[4][3][BSZ];
    __shared__ float dl[BSZ];
    __shared__ unsigned segStart[CBMAX], Pex[CBMAX], wk[CBMAX];
    int t = threadIdx.x, b = blockIdx.x;
    for (int i = t; i < 4 * 3 * BSZ; i += 512) ((float*)acc)[i] = 0.f;
    if (t < BSZ) {
        int g = b * BSZ + t;
        dl[t] = (g < N) ? dinv[g] : 0.f;
    }
    unsigned tot = seg_setup(offD, b, NB, CB, segStart, Pex, wk, 512);
    int rep = t & 3;
    for (unsigned e = t; e < tot; e += 512) {
        unsigned p = dstbin[seg_pos(segStart, Pex, e)];
        int s = (int)(p & SRC_MASK);
        int di = (int)(p >> SRC_BITS);
        float4 v = v4[s];
        float nm = -v.w * dl[di];
        if (nm != 0.f) {
            atomicAdd(&acc[rep][0][di], nm * v.x);
            atomicAdd(&acc[rep][1][di], nm * v.y);
            atomicAdd(&acc[rep][2][di], nm * v.z);
        }
    }
    __syncthreads();
    if (t < BSZ) {
        int g = b * BSZ + t;
        if (g < N) {
            float s0 = acc[0][0][t] + acc[1][0][t] + acc[2][0][t] + acc[3][0][t];
            float s1 = acc[0][1][t] + acc[1][1][t] + acc[2][1][t] + acc[3][1][t];
            float s2 = acc[0][2][t] + acc[1][2][t] + acc[2][2][t] + acc[3][2][t];
            float4 a = a3v[g];
            outv[g] = make_float4(fmaxf(s0 + a.x + b1[0], 0.f),
                                  fmaxf(s1 + a.y + b1[1], 0.f),
                                  fmaxf(s2 + a.z + b1[2], 0.f), dl[t]);
        }
    }
}

// WlT[c][k] = bf16(Wl[k][c]); Wl is [256][512] f32.
__global__ __launch_bounds__(256) void k_prep(const float* __restrict__ Wl,
                                              unsigned short* __restrict__ WlT) {
    __shared__ float tile[32][33];
    int t = threadIdx.x, tx = t & 31, ty = t >> 5;
    int kb = (blockIdx.x & 7) * 32;
    int cb = (blockIdx.x >> 3) * 32;
#pragma unroll
    for (int r = 0; r < 4; r++) {
        int k = kb + ty + r * 8;
        tile[ty + r * 8][tx] = Wl[(size_t)k * 512 + cb + tx];
    }
    __syncthreads();
#pragma unroll
    for (int r = 0; r < 4; r++) {
        int c = cb + ty + r * 8;
        WlT[(size_t)c * 256 + kb + tx] = f2bf(tile[tx][ty + r * 8]);
    }
}

// Fused: t2 gather (bucket b == rows of this block) + h2 + MFMA + out.
__global__ __launch_bounds__(512) void k_final_mfma(
    const float4* __restrict__ h1v, const unsigned* __restrict__ dstbin,
    const unsigned short* __restrict__ offD,
    const float* __restrict__ W0b, const float* __restrict__ W1b,
    const float* __restrict__ b2, const unsigned short* __restrict__ WlT,
    const float* __restrict__ bl, float* __restrict__ out, int N, int NB, int CB) {
    __shared__ unsigned short h2s[128 * 256];  // 64 KB
    __shared__ float4 u4[128][2];
    __shared__ float acc[4][3][BSZ];
    __shared__ float dl[BSZ];
    __shared__ unsigned segStart[CBMAX], Pex[CBMAX], wk[CBMAX];
    char* h2b = (char*)h2s;
    int t = threadIdx.x, b = blockIdx.x;
    int n0 = b * 128;

    if (t < 128) {
        int g = n0 + t;
        float4 hv = (g < N) ? h1v[g] : make_float4(0.f, 0.f, 0.f, 0.f);
        u4[t][0] = hv;
        dl[t] = hv.w;
    }
    for (int i = t; i < 4 * 3 * BSZ; i += 512) ((float*)acc)[i] = 0.f;
    unsigned tot = seg_setup(offD, b, NB, CB, segStart, Pex, wk, 512);
    int rep = t & 3;
    for (unsigned e = t; e < tot; e += 512) {
        unsigned p = dstbin[seg_pos(segStart, Pex, e)];
        int s = (int)(p & SRC_MASK);
        int di = (int)(p >> SRC_BITS);
        float4 v = h1v[s];
        float nm = -v.w * dl[di];
        if (nm != 0.f) {
            atomicAdd(&acc[rep][0][di], nm * v.x);
            atomicAdd(&acc[rep][1][di], nm * v.y);
            atomicAdd(&acc[rep][2][di], nm * v.z);
        }
    }
    __syncthreads();
    if (t < 128) {
        float s0 = acc[0][0][t] + acc[1][0][t] + acc[2][0][t] + acc[3][0][t];
        float s1 = acc[0][1][t] + acc[1][1][t] + acc[2][1][t] + acc[3][1][t];
        float s2 = acc[0][2][t] + acc[1][2][t] + acc[2][2][t] + acc[3][2][t];
        u4[t][1] = make_float4(s0, s1, s2, 0.f);
    }
    __syncthreads();

    {   // phase 1: h2 bf16 -> XOR-swizzled LDS
        int k0 = (t & 127) * 2;
        int rh = (t >> 7) * 32;
        float w00a = W0b[k0],       w00b = W0b[k0 + 1];
        float w01a = W0b[256 + k0], w01b = W0b[256 + k0 + 1];
        float w02a = W0b[512 + k0], w02b = W0b[512 + k0 + 1];
        float w10a = W1b[k0],       w10b = W1b[k0 + 1];
        float w11a = W1b[256 + k0], w11b = W1b[256 + k0 + 1];
        float w12a = W1b[512 + k0], w12b = W1b[512 + k0 + 1];
        float bka = b2[k0], bkb = b2[k0 + 1];
        int kbyte = k0 * 2;
#pragma unroll
        for (int r = 0; r < 32; r++) {
            int rr = rh + r;
            float4 h = u4[rr][0];
            float4 v = u4[rr][1];
            float za = bka + h.x * w00a + h.y * w01a + h.z * w02a
                           + v.x * w10a + v.y * w11a + v.z * w12a;
            float zb = bkb + h.x * w00b + h.y * w01b + h.z * w02b
                           + v.x * w10b + v.y * w11b + v.z * w12b;
            za = fmaxf(za, 0.f); zb = fmaxf(zb, 0.f);
            unsigned pk = ((unsigned)f2bf(zb) << 16) | (unsigned)f2bf(za);
            int byte = rr * 512 + (kbyte ^ ((rr & 7) << 4));
            *(unsigned*)(h2b + byte) = pk;
        }
    }
    __syncthreads();

    // phase 2: wave w -> rows (w&1)*64, cols (w>>1)*128
    int w = t >> 6, l = t & 63;
    int row0 = (w & 1) * 64, col0 = (w >> 1) * 128;
    int lrow = l & 15, lkb = (l >> 4) * 8;
    f32x4 acc2[4][8];
#pragma unroll
    for (int rt = 0; rt < 4; rt++)
#pragma unroll
        for (int ct = 0; ct < 8; ct++) acc2[rt][ct] = (f32x4)0.f;

#pragma unroll
    for (int ks = 0; ks < 8; ks++) {
        int kel = ks * 32 + lkb;
        short8 af[4];
#pragma unroll
        for (int rt = 0; rt < 4; rt++) {
            int r = row0 + rt * 16 + lrow;
            int byte = r * 512 + ((kel * 2) ^ ((r & 7) << 4));
            af[rt] = *(const short8*)(h2b + byte);
        }
        short8 bf[8];
#pragma unroll
        for (int ct = 0; ct < 8; ct++) {
            int c = col0 + ct * 16 + lrow;
            bf[ct] = *(const short8*)(WlT + (size_t)c * 256 + kel);
        }
#pragma unroll
        for (int rt = 0; rt < 4; rt++)
#pragma unroll
            for (int ct = 0; ct < 8; ct++)
                acc2[rt][ct] = __builtin_amdgcn_mfma_f32_16x16x32_bf16(
                    af[rt], bf[ct], acc2[rt][ct], 0, 0, 0);
    }

    float blv[8];
#pragma unroll
    for (int ct = 0; ct < 8; ct++) blv[ct] = bl[col0 + ct * 16 + lrow];
#pragma unroll
    for (int rt = 0; rt < 4; rt++) {
        int rbase = n0 + row0 + rt * 16 + (l >> 4) * 4;
#pragma unroll
        for (int j = 0; j < 4; j++) {
            int row = rbase + j;
            if (row < N) {
                float* orow = out + (size_t)row * 512 + col0 + lrow;
#pragma unroll
                for (int ct = 0; ct < 8; ct++)
                    orow[ct * 16] = acc2[rt][ct][j] + blv[ct];
            }
        }
    }
}

extern "C" void kernel_launch(void* const* d_in, const int* in_sizes, int n_in,
                              void* d_out, int out_size, void* d_ws, size_t ws_size,
                              hipStream_t stream) {
    const float* x   = (const float*)d_in[0];
    const int*   ei  = (const int*)d_in[1];
    const float* W0a = (const float*)d_in[2];
    const float* W1a = (const float*)d_in[3];
    const float* b1  = (const float*)d_in[4];
    const float* W0b = (const float*)d_in[5];
    const float* W1b = (const float*)d_in[6];
    const float* b2  = (const float*)d_in[7];
    const float* Wl  = (const float*)d_in[8];
    const float* bl  = (const float*)d_in[9];
    float* out = (float*)d_out;

    const int N = in_sizes[0] / 64;
    const int E = in_sizes[1] / 2;
    const int NB = (N + BSZ - 1) >> BSH;
    const int CB = (E + SEPB - 1) / SEPB;

    char* base = (char*)d_ws;
    size_t off = 0;
    auto alloc = [&](size_t bytes) {
        void* p = base + off;
        off = (off + bytes + 255) & ~(size_t)255;
        return p;
    };
    unsigned short* offD = (unsigned short*)alloc((size_t)CB * (NB + 1) * 2);
    unsigned short* offS = (unsigned short*)alloc((size_t)CB * (NB + 1) * 2);
    unsigned* dstbin     = (unsigned*)alloc((size_t)CB * SEPB * 4);
    unsigned char* srcbin = (unsigned char*)alloc((size_t)CB * SEPB);
    float* dinv = (float*)alloc((size_t)N * 4);
    float* a3v  = (float*)alloc((size_t)N * 16);
    float* y3v  = (float*)alloc((size_t)N * 16);
    float* h1v  = (float*)alloc((size_t)N * 16);
    unsigned short* WlT = (unsigned short*)alloc(512 * 256 * 2);

    k_prep<<<128, 256, 0, stream>>>(Wl, WlT);
    k_sortlocal<<<CB, 512, 0, stream>>>(ei, E, NB, dstbin, srcbin, offD, offS);
    k_deggemm<<<NB, 256, 0, stream>>>(srcbin, offS, x, W0a, W1a, dinv,
                                      (float4*)a3v, (float4*)y3v, N, NB, CB);
    k_tgather<<<NB, 512, 0, stream>>>(dstbin, offD, (const float4*)y3v, dinv,
                                      (const float4*)a3v, b1, (float4*)h1v, N, NB, CB);
    k_final_mfma<<<NB, 512, 0, stream>>>(
        (const float4*)h1v, dstbin, offD, W0b, W1b, b2, WlT, bl, out, N, NB, CB);
}